// Round 2
// baseline (213.074 us; speedup 1.0000x reference)
//
#include <hip/hip_runtime.h>
#include <math.h>

#define BB 16
#define SS 512
#define INDIM 64
#define DMODEL 64
#define HID 256
#define FILT 32
#define TYY 256
#define TXX 287
#define NT 5
#define NCH 64                  // chunks per batch in k_gpart
#define RIDGEF 0.01f
#define THRESHF 0.005f
#define GRAMN 1088              // per-(b,t): 1056 pitch-33 gram + 32 cross
#define PARTTOT ((size_t)BB * NCH * NT * GRAMN)   // per-chunk partials

// fast tanh: clamped exp2-path (v_exp_f32), |err| ~1e-6, no libcall
__device__ __forceinline__ float ftanh(float v)
{
    float vc = fminf(fmaxf(v, -15.f), 15.f);
    float e = __expf(2.f * vc);
    return (e - 1.f) / (e + 1.f);
}

// ---------------------------------------------------------------------------
// Kernel 1: fused MLP -> LN -> tanh -> W2 -> tanh (e_orig) -> +pos-enc -> q,kT.
// 8 rows/block.  Side-job: block 0 zeros the loss counters.
// ---------------------------------------------------------------------------
__global__ __launch_bounds__(256) void k_mlp(
    const float* __restrict__ fps, const float* __restrict__ W1, const float* __restrict__ b1,
    const float* __restrict__ gamma, const float* __restrict__ beta,
    const float* __restrict__ W2, const float* __restrict__ b2,
    const float* __restrict__ Wq, const float* __restrict__ bq,
    const float* __restrict__ Wk, const float* __restrict__ bk,
    float* __restrict__ e_out, float* __restrict__ q_out, float* __restrict__ kT_out,
    int* __restrict__ ctrs)
{
    const int row0 = blockIdx.x << 3;
    const int tid = threadIdx.x;
    const int wid = tid >> 6, lane = tid & 63;

    if (blockIdx.x == 0 && tid < 4) {
        ctrs[tid] = 0;   // [0]=done_ctr [1]=valid_cnt [2]=loss_sum bits [3]=pad
    }

    __shared__ float fr[8][INDIM];
    __shared__ float th4[8][HID];
    __shared__ float ee4[4][DMODEL];
    __shared__ float part4[4][4][DMODEL];
    __shared__ float partk4[4][4][DMODEL];
    __shared__ float wred[4][8][2];

    { int r = tid >> 6, i = tid & 63;
      fr[r][i]     = fps[(row0 + r) * INDIM + i];
      fr[r + 4][i] = fps[(row0 + r + 4) * INDIM + i]; }
    __syncthreads();

    float h[8];
    float b1v = b1[tid];
    #pragma unroll
    for (int r = 0; r < 8; ++r) h[r] = b1v;
    for (int i = 0; i < INDIM; ++i) {
        float w = W1[i * HID + tid];
        #pragma unroll
        for (int r = 0; r < 8; ++r) h[r] = fmaf(fr[r][i], w, h[r]);
    }

    float s1[8], s2[8];
    #pragma unroll
    for (int r = 0; r < 8; ++r) { s1[r] = h[r]; s2[r] = h[r] * h[r]; }
    #pragma unroll
    for (int off = 1; off < 64; off <<= 1) {
        #pragma unroll
        for (int r = 0; r < 8; ++r) {
            s1[r] += __shfl_xor(s1[r], off);
            s2[r] += __shfl_xor(s2[r], off);
        }
    }
    if (lane == 0) {
        #pragma unroll
        for (int r = 0; r < 8; ++r) { wred[wid][r][0] = s1[r]; wred[wid][r][1] = s2[r]; }
    }
    __syncthreads();
    float gm = gamma[tid], bt = beta[tid];
    #pragma unroll
    for (int r = 0; r < 8; ++r) {
        float t1 = wred[0][r][0] + wred[1][r][0] + wred[2][r][0] + wred[3][r][0];
        float t2 = wred[0][r][1] + wred[1][r][1] + wred[2][r][1] + wred[3][r][1];
        float mu = t1 * (1.0f / HID);
        float var = t2 * (1.0f / HID) - mu * mu;
        float hn = (h[r] - mu) * rsqrtf(var + 1e-5f) * gm + bt;
        th4[r][tid] = ftanh(hn);
    }
    __syncthreads();

    #pragma unroll
    for (int half = 0; half < 2; ++half) {
        const int rbase = half * 4;
        { int p = tid >> 6, j = tid & 63;
          float acc[4] = {0.f, 0.f, 0.f, 0.f};
          for (int i = p * 64; i < p * 64 + 64; ++i) {
              float w = W2[i * DMODEL + j];
              #pragma unroll
              for (int r = 0; r < 4; ++r) acc[r] = fmaf(th4[rbase + r][i], w, acc[r]);
          }
          #pragma unroll
          for (int r = 0; r < 4; ++r) part4[p][r][j] = acc[r];
        }
        __syncthreads();
        { int r = tid >> 6, j = tid & 63;
          float e = part4[0][r][j] + part4[1][r][j] + part4[2][r][j] + part4[3][r][j] + b2[j];
          float eo = ftanh(e);
          int row = row0 + rbase + r;
          int s = row & (SS - 1);
          e_out[(size_t)row * DMODEL + j] = eo;
          float div = __expf(-(float)(j & ~1) * 0.14391156831212787f);  // ln(10000)/64
          float ang = (float)s * div;
          float pe = (j & 1) ? __cosf(ang) : __sinf(ang);
          ee4[r][j] = eo + 0.05f * pe;
        }
        __syncthreads();
        { int p = tid >> 6, j = tid & 63;
          float aq[4] = {0.f,0.f,0.f,0.f}, ak[4] = {0.f,0.f,0.f,0.f};
          for (int i = p * 16; i < p * 16 + 16; ++i) {
              float wqv = Wq[i * DMODEL + j];
              float wkv = Wk[i * DMODEL + j];
              #pragma unroll
              for (int r = 0; r < 4; ++r) {
                  aq[r] = fmaf(ee4[r][i], wqv, aq[r]);
                  ak[r] = fmaf(ee4[r][i], wkv, ak[r]);
              }
          }
          #pragma unroll
          for (int r = 0; r < 4; ++r) { part4[p][r][j] = aq[r]; partk4[p][r][j] = ak[r]; }
        }
        __syncthreads();
        { int r = tid >> 6, j = tid & 63;
          float qv = part4[0][r][j] + part4[1][r][j] + part4[2][r][j] + part4[3][r][j] + bq[j];
          float kv = partk4[0][r][j] + partk4[1][r][j] + partk4[2][r][j] + partk4[3][r][j] + bk[j];
          int row = row0 + rbase + r;
          int b = row >> 9, s = row & (SS - 1);
          q_out[(size_t)row * DMODEL + j] = qv;
          kT_out[(size_t)(b * DMODEL + j) * SS + s] = kv;
        }
        __syncthreads();
    }
}

// ---------------------------------------------------------------------------
// Kernel 2: causal scores + softmax -> alpha f32 into d_out.
// 8 t-rows per block: kT panel L2 reads amortized 8x.
// ---------------------------------------------------------------------------
__global__ __launch_bounds__(256) void k_attn(
    const float* __restrict__ q, const float* __restrict__ kT,
    float* __restrict__ alpha)
{
    const int blk = blockIdx.x;
    const int b = blk >> 6;              // 64 blocks per batch
    const int t0 = (blk & 63) << 3;
    const int t7 = t0 + 7;
    const int tid = threadIdx.x;
    const int wave = tid >> 6, lane = tid & 63;

    __shared__ float qt[8 * DMODEL];
    __shared__ float redm[8][4];

    { size_t qb = (size_t)(b * SS + t0) * DMODEL;
      qt[tid] = q[qb + tid];
      qt[tid + 256] = q[qb + tid + 256]; }
    __syncthreads();

    const float* kTb = kT + (size_t)b * DMODEL * SS;
    const int s0 = tid, s1 = tid + 256;
    float a0[8] = {0,0,0,0,0,0,0,0}, a1[8] = {0,0,0,0,0,0,0,0};
    if (t7 >= 256) {
        for (int d = 0; d < DMODEL; ++d) {
            float k0 = kTb[d * SS + s0];
            float k1 = kTb[d * SS + s1];
            #pragma unroll
            for (int r = 0; r < 8; ++r) {
                float qv = qt[r * DMODEL + d];
                a0[r] = fmaf(qv, k0, a0[r]);
                a1[r] = fmaf(qv, k1, a1[r]);
            }
        }
    } else {
        for (int d = 0; d < DMODEL; ++d) {
            float k0 = kTb[d * SS + s0];
            #pragma unroll
            for (int r = 0; r < 8; ++r)
                a0[r] = fmaf(qt[r * DMODEL + d], k0, a0[r]);
        }
    }
    float lg0[8], lg1[8];
    #pragma unroll
    for (int r = 0; r < 8; ++r) {
        int tr = t0 + r;
        lg0[r] = (s0 <= tr) ? 0.25f * a0[r] : -INFINITY;
        lg1[r] = (s1 <= tr) ? 0.25f * a1[r] : -INFINITY;
    }
    float mr[8];
    #pragma unroll
    for (int r = 0; r < 8; ++r) {
        float m = fmaxf(lg0[r], lg1[r]);
        #pragma unroll
        for (int off = 32; off > 0; off >>= 1) m = fmaxf(m, __shfl_xor(m, off));
        if (lane == 0) redm[r][wave] = m;
    }
    __syncthreads();
    #pragma unroll
    for (int r = 0; r < 8; ++r)
        mr[r] = fmaxf(fmaxf(redm[r][0], redm[r][1]), fmaxf(redm[r][2], redm[r][3]));
    __syncthreads();
    float ex0[8], ex1[8], sr[8];
    #pragma unroll
    for (int r = 0; r < 8; ++r) {
        ex0[r] = __expf(lg0[r] - mr[r]);   // exp(-inf) = 0 for masked
        ex1[r] = __expf(lg1[r] - mr[r]);
        float sm = ex0[r] + ex1[r];
        #pragma unroll
        for (int off = 32; off > 0; off >>= 1) sm += __shfl_xor(sm, off);
        if (lane == 0) redm[r][wave] = sm;
    }
    __syncthreads();
    #pragma unroll
    for (int r = 0; r < 8; ++r)
        sr[r] = redm[r][0] + redm[r][1] + redm[r][2] + redm[r][3];
    #pragma unroll
    for (int r = 0; r < 8; ++r) {
        float inv = 1.0f / sr[r];
        size_t base = (size_t)(b * SS + t0 + r) * SS;
        alpha[base + s0] = ex0[r] * inv;
        alpha[base + s1] = ex1[r] * inv;
    }
}

// ---------------------------------------------------------------------------
// Kernel 3: per (b, s-chunk); float4 dot loops, prefix-scan diagonals,
// register acc.  NO atomics: writes per-chunk partial gram/cross to ws
// (zeros when inactive); k_solve2 sums the 64 chunk partials.
// ---------------------------------------------------------------------------
__global__ __launch_bounds__(256) void k_gpart(
    const float* __restrict__ x, const float* __restrict__ y,
    const int* __restrict__ steps, const float* __restrict__ alpha,
    float* __restrict__ part, int C, int CS)
{
    const int b = blockIdx.x / C;
    const int chunk = blockIdx.x % C;
    const int tid = threadIdx.x;
    const int lane = tid & 63, wid = tid >> 6;

    __shared__ __align__(16) float xs[288];
    __shared__ __align__(16) float ys[256];
    __shared__ float Gs[1056];        // 32x33 (pitch 33)
    __shared__ float crossL[32];
    __shared__ float wv[NT * 64];
    __shared__ int sl[64];
    __shared__ int nselS;
    __shared__ int stS[NT];
    __shared__ float redA[4][33];
    __shared__ float redB[4][33];

    if (tid < NT) stS[tid] = steps[tid];
    if (tid < 32) Gs[tid * 33 + 32] = 0.f;
    __syncthreads();

    for (int idx = tid; idx < NT * CS; idx += 256) {
        int t = idx / CS, si = idx % CS;
        float a = alpha[(size_t)(b * SS + stS[t]) * SS + chunk * CS + si];
        wv[t * 64 + si] = (a > THRESHF) ? a : 0.f;
    }
    __syncthreads();
    if (wid == 0) {
        float m = 0.f;
        if (lane < CS)
            m = wv[lane] + wv[64 + lane] + wv[128 + lane] + wv[192 + lane] + wv[256 + lane];
        unsigned long long mask = __ballot(m > 0.f);
        if (m > 0.f) {
            int pos = __popcll(mask & ((1ull << lane) - 1ull));
            sl[pos] = lane;
        }
        if (lane == 0) nselS = __popcll(mask);
    }
    __syncthreads();
    const int nsel = nselS;

    float acc[NT][5];
    #pragma unroll
    for (int t = 0; t < NT; ++t) {
        #pragma unroll
        for (int r = 0; r < 5; ++r) acc[t][r] = 0.f;
    }

    float rx0 = 0.f, rx1 = 0.f, ry = 0.f;
    if (nsel > 0) {
        int sg = chunk * CS + sl[0];
        const float* xr = x + (size_t)(b * SS + sg) * TXX;
        const float* yr = y + (size_t)(b * SS + sg) * TYY;
        rx0 = xr[tid];
        if (tid < 31) rx1 = xr[256 + tid];
        ry = yr[tid];
    }

    for (int i = 0; i < nsel; ++i) {
        xs[tid] = rx0;
        if (tid < 31) xs[256 + tid] = rx1;
        ys[tid] = ry;
        const int sl_cur = sl[i];
        __syncthreads();

        if (i + 1 < nsel) {
            int sg = chunk * CS + sl[i + 1];
            const float* xr = x + (size_t)(b * SS + sg) * TXX;
            const float* yr = y + (size_t)(b * SS + sg) * TYY;
            rx0 = xr[tid];
            if (tid < 31) rx1 = xr[256 + tid];
            ry = yr[tid];
        }

        { int l = tid & 31, p = tid >> 5;
          const float4* xk4 = (const float4*)(xs + (p << 5));
          const float4* yk4 = (const float4*)(ys + (p << 5));
          float c = 0.f, a = 0.f;
          #pragma unroll
          for (int j = 0; j < 8; ++j) {
              float4 xk = xk4[j];
              float4 yk = yk4[j];
              int kb = (p << 5) + (j << 2);
              float x0 = xs[kb + l],     x1 = xs[kb + 1 + l];
              float x2 = xs[kb + 2 + l], x3 = xs[kb + 3 + l];
              c = fmaf(x0, yk.x, c); a = fmaf(xk.x, x0, a);
              c = fmaf(x1, yk.y, c); a = fmaf(xk.y, x1, a);
              c = fmaf(x2, yk.z, c); a = fmaf(xk.z, x2, a);
              c = fmaf(x3, yk.w, c); a = fmaf(xk.w, x3, a);
          }
          c += __shfl_xor(c, 32);
          a += __shfl_xor(a, 32);
          if (lane < 32) { redA[wid][l] = c; redB[wid][l] = a; }
        }
        __syncthreads();

        if (tid < 32)
            crossL[tid] = redA[0][tid] + redA[1][tid] + redA[2][tid] + redA[3][tid];

        { int jj = lane & 31;
          #pragma unroll
          for (int pass = 0; pass < 4; ++pass) {
              int dd = 2 * (wid + 4 * pass) + (lane >> 5);
              float g0 = redB[0][dd] + redB[1][dd] + redB[2][dd] + redB[3][dd];
              float dlt = 0.f;
              if (jj > 0 && jj + dd < 32)
                  dlt = xs[jj + 255] * xs[jj + 255 + dd]
                      - xs[jj - 1] * xs[jj - 1 + dd];
              #pragma unroll
              for (int off = 1; off < 32; off <<= 1) {
                  float tsh = __shfl_up(dlt, off, 32);
                  if (jj >= off) dlt += tsh;
              }
              if (jj + dd < 32) {
                  float gval = g0 + dlt;
                  Gs[jj * 33 + jj + dd] = gval;
                  Gs[(jj + dd) * 33 + jj] = gval;
              }
          }
        }
        __syncthreads();

        { float g0 = Gs[tid], g1 = Gs[tid + 256], g2 = Gs[tid + 512], g3 = Gs[tid + 768];
          float g4 = (tid < 32) ? Gs[1024 + tid]
                   : ((tid < 64) ? crossL[tid - 32] : 0.f);
          #pragma unroll
          for (int t = 0; t < NT; ++t) {
              float w = wv[t * 64 + sl_cur];
              if (w > 0.f) {
                  acc[t][0] = fmaf(w, g0, acc[t][0]);
                  acc[t][1] = fmaf(w, g1, acc[t][1]);
                  acc[t][2] = fmaf(w, g2, acc[t][2]);
                  acc[t][3] = fmaf(w, g3, acc[t][3]);
                  acc[t][4] = fmaf(w, g4, acc[t][4]);
              }
          }
        }
    }

    // Unconditional partial write (zeros when this chunk contributed nothing).
    #pragma unroll
    for (int t = 0; t < NT; ++t) {
        float* gr = part + ((size_t)(b * C + chunk) * NT + t) * GRAMN;
        #pragma unroll
        for (int r = 0; r < 4; ++r) gr[tid + 256 * r] = acc[t][r];
        if (tid < 64) gr[1024 + tid] = acc[t][4];
    }
}

// ---------------------------------------------------------------------------
// Kernel 4: per (b,t): sum 64 chunk partials -> gram + ridge, single-wave
// register Cholesky, shuffle solves, prediction loss; masked-mean via
// atomics + last-block.
// ---------------------------------------------------------------------------
__global__ __launch_bounds__(256) void k_solve2(
    const float* __restrict__ x, const float* __restrict__ y,
    const int* __restrict__ steps, const float* __restrict__ alpha,
    const float* __restrict__ part,
    int* __restrict__ ctrs, float* __restrict__ out0)
{
    const int g = blockIdx.x;
    const int b = g / NT, t = g % NT;
    const int tid = threadIdx.x;

    __shared__ float Af[1056];   // pitch 33
    __shared__ float zs[FILT];
    __shared__ float wt[FILT];
    __shared__ float xsr[TXX + 1];
    __shared__ float red[256];
    __shared__ int step_s;
    __shared__ int anyv;

    if (tid == 0) { step_s = steps[t]; anyv = 0; }
    __syncthreads();

    // Sum the 64 per-chunk partials (deterministic; replaces atomicAdd gram).
    { const float* pb = part + ((size_t)b * NCH * NT + t) * GRAMN;
      float s0 = 0.f, s1 = 0.f, s2 = 0.f, s3 = 0.f, s4 = 0.f;
      #pragma unroll 4
      for (int p = 0; p < NCH; ++p) {
          const float* rp = pb + (size_t)p * (NT * GRAMN);
          s0 += rp[tid];
          s1 += rp[tid + 256];
          s2 += rp[tid + 512];
          s3 += rp[tid + 768];
          if (tid < 64) s4 += rp[1024 + tid];
      }
      Af[tid]       = s0;
      Af[tid + 256] = s1;
      Af[tid + 512] = s2;
      Af[tid + 768] = s3;
      if (tid < 32) Af[1024 + tid] = s4;
      else if (tid < 64) zs[tid - 32] = s4;
    }

    { const float* arow = alpha + (size_t)(b * SS + step_s) * SS;
      if (arow[tid] > THRESHF || arow[tid + 256] > THRESHF) anyv = 1; }
    __syncthreads();
    if (tid < 32) Af[tid * 33 + tid] += RIDGEF;
    __syncthreads();

    if (tid < 32) {
        float a[32];
        #pragma unroll
        for (int j = 0; j < 32; ++j) a[j] = Af[tid * 33 + j];
        #pragma unroll
        for (int k = 0; k < 32; ++k) {
            float akk = __shfl(a[k], k);
            float dk = sqrtf(akk);
            float ck = a[k] / dk;
            if (tid >= k) a[k] = ck;
            #pragma unroll
            for (int m = k + 1; m < 32; ++m) {
                float cm = __shfl(ck, m);
                if (tid >= m) a[m] = fmaf(-ck, cm, a[m]);
            }
        }
        #pragma unroll
        for (int j = 0; j < 32; ++j)
            if (j <= tid) Af[tid * 33 + j] = a[j];

        float zl = zs[tid];
        #pragma unroll
        for (int k = 0; k < 32; ++k) {
            float akk = __shfl(a[k], k);
            float zk = __shfl(zl, k) / akk;
            if (tid == k) zl = zk;
            else if (tid > k) zl = fmaf(-a[k], zk, zl);
        }
        #pragma unroll
        for (int k = 31; k >= 0; --k) {
            float akk = __shfl(a[k], k);
            float wk = __shfl(zl, k) / akk;
            if (tid == k) zl = wk;
            else if (tid < k) zl = fmaf(-Af[k * 33 + tid], wk, zl);
        }
        wt[tid] = zl;
    }
    __syncthreads();

    const int sstep = step_s;
    const float* xrow = x + (size_t)(b * SS + sstep) * TXX;
    for (int i = tid; i < TXX; i += 256) xsr[i] = xrow[i];
    __syncthreads();
    float pk = 0.f;
    #pragma unroll
    for (int l = 0; l < FILT; ++l) pk = fmaf(xsr[tid + l], wt[l], pk);
    float d = y[(size_t)(b * SS + sstep) * TYY + tid] - pk;
    red[tid] = d * d;
    __syncthreads();
    for (int off = 128; off > 0; off >>= 1) {
        if (tid < off) red[tid] += red[tid + off];
        __syncthreads();
    }
    if (tid == 0) {
        float lossval = red[0] * (1.0f / TYY);
        float* loss_sum = (float*)(ctrs + 2);
        if (anyv) {
            atomicAdd(loss_sum, lossval);
            atomicAdd(&ctrs[1], 1);
        }
        __threadfence();
        int prev = atomicAdd(&ctrs[0], 1);
        if (prev == BB * NT - 1) {
            float s = atomicAdd(loss_sum, 0.0f);     // atomic read (device-coherent)
            int c = atomicAdd(&ctrs[1], 0);
            out0[0] = s / (float)(c > 0 ? c : 1);
        }
    }
}

extern "C" void kernel_launch(void* const* d_in, const int* in_sizes, int n_in,
                              void* d_out, int out_size, void* d_ws, size_t ws_size,
                              hipStream_t stream)
{
    const float* fps  = (const float*)d_in[0];
    const float* x    = (const float*)d_in[1];
    const float* y    = (const float*)d_in[2];
    const int* steps  = (const int*)d_in[3];
    const float* W1   = (const float*)d_in[4];
    const float* b1   = (const float*)d_in[5];
    const float* gamma= (const float*)d_in[6];
    const float* beta = (const float*)d_in[7];
    const float* W2   = (const float*)d_in[8];
    const float* b2   = (const float*)d_in[9];
    const float* Wq   = (const float*)d_in[10];
    const float* bq   = (const float*)d_in[11];
    const float* Wk   = (const float*)d_in[12];
    const float* bk   = (const float*)d_in[13];

    // Output f32 flat: [loss(1) | alpha(B*S*S) | e_orig(B*S*D)]
    float* out   = (float*)d_out;
    float* alpha = out + 1;
    float* e_out = out + 1 + (size_t)BB * SS * SS;

    // ws: [part(B*NCH*NT*1088) | ctrs(4 int) | q | kT]   (~26.5 MB of 256 MB)
    float* part = (float*)d_ws;
    int*   ctrs = (int*)(part + PARTTOT);
    float* q    = (float*)(ctrs + 4);
    float* kT   = q + (size_t)BB * SS * DMODEL;

    const int C = NCH, CS = SS / NCH;

    hipLaunchKernelGGL(k_mlp, dim3(BB * SS / 8), dim3(256), 0, stream,
                       fps, W1, b1, gamma, beta, W2, b2, Wq, bq, Wk, bk,
                       e_out, q, kT, ctrs);
    hipLaunchKernelGGL(k_attn, dim3(BB * (SS / 8)), dim3(256), 0, stream,
                       q, kT, alpha);
    hipLaunchKernelGGL(k_gpart, dim3(BB * C), dim3(256), 0, stream,
                       x, y, steps, alpha, part, C, CS);
    hipLaunchKernelGGL(k_solve2, dim3(BB * NT), dim3(256), 0, stream,
                       x, y, steps, alpha, part, ctrs, out);
}

// Round 3
// 200.323 us; speedup vs baseline: 1.0637x; 1.0637x over previous
//
#include <hip/hip_runtime.h>
#include <math.h>

#define BB 16
#define SS 512
#define INDIM 64
#define DMODEL 64
#define HID 256
#define FILT 32
#define TYY 256
#define TXX 287
#define NT 5
#define NCH 64                  // chunks per batch in k_gpart
#define RIDGEF 0.01f
#define THRESHF 0.005f
#define GRAMN 1088              // per-(b,t): 1056 pitch-33 gram + 32 cross
#define PARTTOT ((size_t)BB * NCH * NT * GRAMN)   // per-chunk partials
#define GRAMTOT ((size_t)BB * NT * GRAMN)

// fast tanh: clamped exp2-path (v_exp_f32), |err| ~1e-6, no libcall
__device__ __forceinline__ float ftanh(float v)
{
    float vc = fminf(fmaxf(v, -15.f), 15.f);
    float e = __expf(2.f * vc);
    return (e - 1.f) / (e + 1.f);
}

// ---------------------------------------------------------------------------
// Kernel 1: fused MLP -> LN -> tanh -> W2 -> tanh (e_orig) -> +pos-enc -> q,kT.
// 8 rows/block.  Side-job: block 0 zeros the loss counters.
// ---------------------------------------------------------------------------
__global__ __launch_bounds__(256) void k_mlp(
    const float* __restrict__ fps, const float* __restrict__ W1, const float* __restrict__ b1,
    const float* __restrict__ gamma, const float* __restrict__ beta,
    const float* __restrict__ W2, const float* __restrict__ b2,
    const float* __restrict__ Wq, const float* __restrict__ bq,
    const float* __restrict__ Wk, const float* __restrict__ bk,
    float* __restrict__ e_out, float* __restrict__ q_out, float* __restrict__ kT_out,
    int* __restrict__ ctrs)
{
    const int row0 = blockIdx.x << 3;
    const int tid = threadIdx.x;
    const int wid = tid >> 6, lane = tid & 63;

    if (blockIdx.x == 0 && tid < 4) {
        ctrs[tid] = 0;   // [0]=done_ctr [1]=valid_cnt [2]=loss_sum bits [3]=pad
    }

    __shared__ float fr[8][INDIM];
    __shared__ float th4[8][HID];
    __shared__ float ee4[4][DMODEL];
    __shared__ float part4[4][4][DMODEL];
    __shared__ float partk4[4][4][DMODEL];
    __shared__ float wred[4][8][2];

    { int r = tid >> 6, i = tid & 63;
      fr[r][i]     = fps[(row0 + r) * INDIM + i];
      fr[r + 4][i] = fps[(row0 + r + 4) * INDIM + i]; }
    __syncthreads();

    float h[8];
    float b1v = b1[tid];
    #pragma unroll
    for (int r = 0; r < 8; ++r) h[r] = b1v;
    for (int i = 0; i < INDIM; ++i) {
        float w = W1[i * HID + tid];
        #pragma unroll
        for (int r = 0; r < 8; ++r) h[r] = fmaf(fr[r][i], w, h[r]);
    }

    float s1[8], s2[8];
    #pragma unroll
    for (int r = 0; r < 8; ++r) { s1[r] = h[r]; s2[r] = h[r] * h[r]; }
    #pragma unroll
    for (int off = 1; off < 64; off <<= 1) {
        #pragma unroll
        for (int r = 0; r < 8; ++r) {
            s1[r] += __shfl_xor(s1[r], off);
            s2[r] += __shfl_xor(s2[r], off);
        }
    }
    if (lane == 0) {
        #pragma unroll
        for (int r = 0; r < 8; ++r) { wred[wid][r][0] = s1[r]; wred[wid][r][1] = s2[r]; }
    }
    __syncthreads();
    float gm = gamma[tid], bt = beta[tid];
    #pragma unroll
    for (int r = 0; r < 8; ++r) {
        float t1 = wred[0][r][0] + wred[1][r][0] + wred[2][r][0] + wred[3][r][0];
        float t2 = wred[0][r][1] + wred[1][r][1] + wred[2][r][1] + wred[3][r][1];
        float mu = t1 * (1.0f / HID);
        float var = t2 * (1.0f / HID) - mu * mu;
        float hn = (h[r] - mu) * rsqrtf(var + 1e-5f) * gm + bt;
        th4[r][tid] = ftanh(hn);
    }
    __syncthreads();

    #pragma unroll
    for (int half = 0; half < 2; ++half) {
        const int rbase = half * 4;
        { int p = tid >> 6, j = tid & 63;
          float acc[4] = {0.f, 0.f, 0.f, 0.f};
          for (int i = p * 64; i < p * 64 + 64; ++i) {
              float w = W2[i * DMODEL + j];
              #pragma unroll
              for (int r = 0; r < 4; ++r) acc[r] = fmaf(th4[rbase + r][i], w, acc[r]);
          }
          #pragma unroll
          for (int r = 0; r < 4; ++r) part4[p][r][j] = acc[r];
        }
        __syncthreads();
        { int r = tid >> 6, j = tid & 63;
          float e = part4[0][r][j] + part4[1][r][j] + part4[2][r][j] + part4[3][r][j] + b2[j];
          float eo = ftanh(e);
          int row = row0 + rbase + r;
          int s = row & (SS - 1);
          e_out[(size_t)row * DMODEL + j] = eo;
          float div = __expf(-(float)(j & ~1) * 0.14391156831212787f);  // ln(10000)/64
          float ang = (float)s * div;
          float pe = (j & 1) ? __cosf(ang) : __sinf(ang);
          ee4[r][j] = eo + 0.05f * pe;
        }
        __syncthreads();
        { int p = tid >> 6, j = tid & 63;
          float aq[4] = {0.f,0.f,0.f,0.f}, ak[4] = {0.f,0.f,0.f,0.f};
          for (int i = p * 16; i < p * 16 + 16; ++i) {
              float wqv = Wq[i * DMODEL + j];
              float wkv = Wk[i * DMODEL + j];
              #pragma unroll
              for (int r = 0; r < 4; ++r) {
                  aq[r] = fmaf(ee4[r][i], wqv, aq[r]);
                  ak[r] = fmaf(ee4[r][i], wkv, ak[r]);
              }
          }
          #pragma unroll
          for (int r = 0; r < 4; ++r) { part4[p][r][j] = aq[r]; partk4[p][r][j] = ak[r]; }
        }
        __syncthreads();
        { int r = tid >> 6, j = tid & 63;
          float qv = part4[0][r][j] + part4[1][r][j] + part4[2][r][j] + part4[3][r][j] + bq[j];
          float kv = partk4[0][r][j] + partk4[1][r][j] + partk4[2][r][j] + partk4[3][r][j] + bk[j];
          int row = row0 + rbase + r;
          int b = row >> 9, s = row & (SS - 1);
          q_out[(size_t)row * DMODEL + j] = qv;
          kT_out[(size_t)(b * DMODEL + j) * SS + s] = kv;
        }
        __syncthreads();
    }
}

// ---------------------------------------------------------------------------
// Kernel 2: causal scores + softmax -> alpha f32 into d_out.
// 8 t-rows per block: kT panel L2 reads amortized 8x.
// ---------------------------------------------------------------------------
__global__ __launch_bounds__(256) void k_attn(
    const float* __restrict__ q, const float* __restrict__ kT,
    float* __restrict__ alpha)
{
    const int blk = blockIdx.x;
    const int b = blk >> 6;              // 64 blocks per batch
    const int t0 = (blk & 63) << 3;
    const int t7 = t0 + 7;
    const int tid = threadIdx.x;
    const int wave = tid >> 6, lane = tid & 63;

    __shared__ float qt[8 * DMODEL];
    __shared__ float redm[8][4];

    { size_t qb = (size_t)(b * SS + t0) * DMODEL;
      qt[tid] = q[qb + tid];
      qt[tid + 256] = q[qb + tid + 256]; }
    __syncthreads();

    const float* kTb = kT + (size_t)b * DMODEL * SS;
    const int s0 = tid, s1 = tid + 256;
    float a0[8] = {0,0,0,0,0,0,0,0}, a1[8] = {0,0,0,0,0,0,0,0};
    if (t7 >= 256) {
        for (int d = 0; d < DMODEL; ++d) {
            float k0 = kTb[d * SS + s0];
            float k1 = kTb[d * SS + s1];
            #pragma unroll
            for (int r = 0; r < 8; ++r) {
                float qv = qt[r * DMODEL + d];
                a0[r] = fmaf(qv, k0, a0[r]);
                a1[r] = fmaf(qv, k1, a1[r]);
            }
        }
    } else {
        for (int d = 0; d < DMODEL; ++d) {
            float k0 = kTb[d * SS + s0];
            #pragma unroll
            for (int r = 0; r < 8; ++r)
                a0[r] = fmaf(qt[r * DMODEL + d], k0, a0[r]);
        }
    }
    float lg0[8], lg1[8];
    #pragma unroll
    for (int r = 0; r < 8; ++r) {
        int tr = t0 + r;
        lg0[r] = (s0 <= tr) ? 0.25f * a0[r] : -INFINITY;
        lg1[r] = (s1 <= tr) ? 0.25f * a1[r] : -INFINITY;
    }
    float mr[8];
    #pragma unroll
    for (int r = 0; r < 8; ++r) {
        float m = fmaxf(lg0[r], lg1[r]);
        #pragma unroll
        for (int off = 32; off > 0; off >>= 1) m = fmaxf(m, __shfl_xor(m, off));
        if (lane == 0) redm[r][wave] = m;
    }
    __syncthreads();
    #pragma unroll
    for (int r = 0; r < 8; ++r)
        mr[r] = fmaxf(fmaxf(redm[r][0], redm[r][1]), fmaxf(redm[r][2], redm[r][3]));
    __syncthreads();
    float ex0[8], ex1[8], sr[8];
    #pragma unroll
    for (int r = 0; r < 8; ++r) {
        ex0[r] = __expf(lg0[r] - mr[r]);   // exp(-inf) = 0 for masked
        ex1[r] = __expf(lg1[r] - mr[r]);
        float sm = ex0[r] + ex1[r];
        #pragma unroll
        for (int off = 32; off > 0; off >>= 1) sm += __shfl_xor(sm, off);
        if (lane == 0) redm[r][wave] = sm;
    }
    __syncthreads();
    #pragma unroll
    for (int r = 0; r < 8; ++r)
        sr[r] = redm[r][0] + redm[r][1] + redm[r][2] + redm[r][3];
    #pragma unroll
    for (int r = 0; r < 8; ++r) {
        float inv = 1.0f / sr[r];
        size_t base = (size_t)(b * SS + t0 + r) * SS;
        alpha[base + s0] = ex0[r] * inv;
        alpha[base + s1] = ex1[r] * inv;
    }
}

// ---------------------------------------------------------------------------
// Kernel 3: per (b, s-chunk); float4 dot loops, prefix-scan diagonals,
// register acc.  NO atomics: writes per-chunk partial gram/cross to ws.
// ---------------------------------------------------------------------------
__global__ __launch_bounds__(256) void k_gpart(
    const float* __restrict__ x, const float* __restrict__ y,
    const int* __restrict__ steps, const float* __restrict__ alpha,
    float* __restrict__ part, int C, int CS)
{
    const int b = blockIdx.x / C;
    const int chunk = blockIdx.x % C;
    const int tid = threadIdx.x;
    const int lane = tid & 63, wid = tid >> 6;

    __shared__ __align__(16) float xs[288];
    __shared__ __align__(16) float ys[256];
    __shared__ float Gs[1056];        // 32x33 (pitch 33)
    __shared__ float crossL[32];
    __shared__ float wv[NT * 64];
    __shared__ int sl[64];
    __shared__ int nselS;
    __shared__ int stS[NT];
    __shared__ float redA[4][33];
    __shared__ float redB[4][33];

    if (tid < NT) stS[tid] = steps[tid];
    if (tid < 32) Gs[tid * 33 + 32] = 0.f;
    __syncthreads();

    for (int idx = tid; idx < NT * CS; idx += 256) {
        int t = idx / CS, si = idx % CS;
        float a = alpha[(size_t)(b * SS + stS[t]) * SS + chunk * CS + si];
        wv[t * 64 + si] = (a > THRESHF) ? a : 0.f;
    }
    __syncthreads();
    if (wid == 0) {
        float m = 0.f;
        if (lane < CS)
            m = wv[lane] + wv[64 + lane] + wv[128 + lane] + wv[192 + lane] + wv[256 + lane];
        unsigned long long mask = __ballot(m > 0.f);
        if (m > 0.f) {
            int pos = __popcll(mask & ((1ull << lane) - 1ull));
            sl[pos] = lane;
        }
        if (lane == 0) nselS = __popcll(mask);
    }
    __syncthreads();
    const int nsel = nselS;

    float acc[NT][5];
    #pragma unroll
    for (int t = 0; t < NT; ++t) {
        #pragma unroll
        for (int r = 0; r < 5; ++r) acc[t][r] = 0.f;
    }

    float rx0 = 0.f, rx1 = 0.f, ry = 0.f;
    if (nsel > 0) {
        int sg = chunk * CS + sl[0];
        const float* xr = x + (size_t)(b * SS + sg) * TXX;
        const float* yr = y + (size_t)(b * SS + sg) * TYY;
        rx0 = xr[tid];
        if (tid < 31) rx1 = xr[256 + tid];
        ry = yr[tid];
    }

    for (int i = 0; i < nsel; ++i) {
        xs[tid] = rx0;
        if (tid < 31) xs[256 + tid] = rx1;
        ys[tid] = ry;
        const int sl_cur = sl[i];
        __syncthreads();

        if (i + 1 < nsel) {
            int sg = chunk * CS + sl[i + 1];
            const float* xr = x + (size_t)(b * SS + sg) * TXX;
            const float* yr = y + (size_t)(b * SS + sg) * TYY;
            rx0 = xr[tid];
            if (tid < 31) rx1 = xr[256 + tid];
            ry = yr[tid];
        }

        { int l = tid & 31, p = tid >> 5;
          const float4* xk4 = (const float4*)(xs + (p << 5));
          const float4* yk4 = (const float4*)(ys + (p << 5));
          float c = 0.f, a = 0.f;
          #pragma unroll
          for (int j = 0; j < 8; ++j) {
              float4 xk = xk4[j];
              float4 yk = yk4[j];
              int kb = (p << 5) + (j << 2);
              float x0 = xs[kb + l],     x1 = xs[kb + 1 + l];
              float x2 = xs[kb + 2 + l], x3 = xs[kb + 3 + l];
              c = fmaf(x0, yk.x, c); a = fmaf(xk.x, x0, a);
              c = fmaf(x1, yk.y, c); a = fmaf(xk.y, x1, a);
              c = fmaf(x2, yk.z, c); a = fmaf(xk.z, x2, a);
              c = fmaf(x3, yk.w, c); a = fmaf(xk.w, x3, a);
          }
          c += __shfl_xor(c, 32);
          a += __shfl_xor(a, 32);
          if (lane < 32) { redA[wid][l] = c; redB[wid][l] = a; }
        }
        __syncthreads();

        if (tid < 32)
            crossL[tid] = redA[0][tid] + redA[1][tid] + redA[2][tid] + redA[3][tid];

        { int jj = lane & 31;
          #pragma unroll
          for (int pass = 0; pass < 4; ++pass) {
              int dd = 2 * (wid + 4 * pass) + (lane >> 5);
              float g0 = redB[0][dd] + redB[1][dd] + redB[2][dd] + redB[3][dd];
              float dlt = 0.f;
              if (jj > 0 && jj + dd < 32)
                  dlt = xs[jj + 255] * xs[jj + 255 + dd]
                      - xs[jj - 1] * xs[jj - 1 + dd];
              #pragma unroll
              for (int off = 1; off < 32; off <<= 1) {
                  float tsh = __shfl_up(dlt, off, 32);
                  if (jj >= off) dlt += tsh;
              }
              if (jj + dd < 32) {
                  float gval = g0 + dlt;
                  Gs[jj * 33 + jj + dd] = gval;
                  Gs[(jj + dd) * 33 + jj] = gval;
              }
          }
        }
        __syncthreads();

        { float g0 = Gs[tid], g1 = Gs[tid + 256], g2 = Gs[tid + 512], g3 = Gs[tid + 768];
          float g4 = (tid < 32) ? Gs[1024 + tid]
                   : ((tid < 64) ? crossL[tid - 32] : 0.f);
          #pragma unroll
          for (int t = 0; t < NT; ++t) {
              float w = wv[t * 64 + sl_cur];
              if (w > 0.f) {
                  acc[t][0] = fmaf(w, g0, acc[t][0]);
                  acc[t][1] = fmaf(w, g1, acc[t][1]);
                  acc[t][2] = fmaf(w, g2, acc[t][2]);
                  acc[t][3] = fmaf(w, g3, acc[t][3]);
                  acc[t][4] = fmaf(w, g4, acc[t][4]);
              }
          }
        }
    }

    // Unconditional partial write (zeros when this chunk contributed nothing).
    #pragma unroll
    for (int t = 0; t < NT; ++t) {
        float* gr = part + ((size_t)(b * C + chunk) * NT + t) * GRAMN;
        #pragma unroll
        for (int r = 0; r < 4; ++r) gr[tid + 256 * r] = acc[t][r];
        if (tid < 64) gr[1024 + tid] = acc[t][4];
    }
}

// ---------------------------------------------------------------------------
// Kernel 3.5: fold the 64 per-chunk partials -> gram.  High-TLP streaming
// reduction: 170 blocks, one float2 output element per thread, 64
// independent strided loads (latency-bound fold removed from k_solve2,
// which had only 80 blocks and ran at 3% HBM BW).
// Chunk order p=0..63 sequential: summation order identical to round-2 fold.
// ---------------------------------------------------------------------------
__global__ __launch_bounds__(256) void k_reduce(
    const float* __restrict__ part, float* __restrict__ gram)
{
    const int e = blockIdx.x * 256 + threadIdx.x;   // 0 .. 80*544-1
    const int g = e / (GRAMN / 2);                  // 0..79  (b*NT+t)
    const int i2 = e - g * (GRAMN / 2);
    const int b = g / NT, t = g - b * NT;

    const float2* src = (const float2*)(part + ((size_t)b * NCH * NT + t) * GRAMN) + i2;
    const size_t stride2 = (size_t)NT * GRAMN / 2;  // float2 stride between chunks

    float sx = 0.f, sy = 0.f;
    #pragma unroll 16
    for (int p = 0; p < NCH; ++p) {
        float2 v = src[(size_t)p * stride2];
        sx += v.x; sy += v.y;
    }
    float2 o; o.x = sx; o.y = sy;
    ((float2*)gram)[(size_t)g * (GRAMN / 2) + i2] = o;
}

// ---------------------------------------------------------------------------
// Kernel 4: per (b,t): gram row + ridge, single-wave register Cholesky,
// shuffle solves, prediction loss; masked-mean via atomics + last-block.
// ---------------------------------------------------------------------------
__global__ __launch_bounds__(256) void k_solve2(
    const float* __restrict__ x, const float* __restrict__ y,
    const int* __restrict__ steps, const float* __restrict__ alpha,
    const float* __restrict__ gram,
    int* __restrict__ ctrs, float* __restrict__ out0)
{
    const int g = blockIdx.x;
    const int b = g / NT, t = g % NT;
    const int tid = threadIdx.x;

    __shared__ float Af[1056];   // pitch 33
    __shared__ float zs[FILT];
    __shared__ float wt[FILT];
    __shared__ float xsr[TXX + 1];
    __shared__ float red[256];
    __shared__ int step_s;
    __shared__ int anyv;

    if (tid == 0) { step_s = steps[t]; anyv = 0; }
    __syncthreads();

    const float* row = gram + (size_t)g * GRAMN;
    Af[tid] = row[tid];
    Af[tid + 256] = row[tid + 256];
    Af[tid + 512] = row[tid + 512];
    Af[tid + 768] = row[tid + 768];
    if (tid < 32) Af[1024 + tid] = row[1024 + tid];
    else if (tid < 64) zs[tid - 32] = row[1024 + tid];

    { const float* arow = alpha + (size_t)(b * SS + step_s) * SS;
      if (arow[tid] > THRESHF || arow[tid + 256] > THRESHF) anyv = 1; }
    __syncthreads();
    if (tid < 32) Af[tid * 33 + tid] += RIDGEF;
    __syncthreads();

    if (tid < 32) {
        float a[32];
        #pragma unroll
        for (int j = 0; j < 32; ++j) a[j] = Af[tid * 33 + j];
        #pragma unroll
        for (int k = 0; k < 32; ++k) {
            float akk = __shfl(a[k], k);
            float dk = sqrtf(akk);
            float ck = a[k] / dk;
            if (tid >= k) a[k] = ck;
            #pragma unroll
            for (int m = k + 1; m < 32; ++m) {
                float cm = __shfl(ck, m);
                if (tid >= m) a[m] = fmaf(-ck, cm, a[m]);
            }
        }
        #pragma unroll
        for (int j = 0; j < 32; ++j)
            if (j <= tid) Af[tid * 33 + j] = a[j];

        float zl = zs[tid];
        #pragma unroll
        for (int k = 0; k < 32; ++k) {
            float akk = __shfl(a[k], k);
            float zk = __shfl(zl, k) / akk;
            if (tid == k) zl = zk;
            else if (tid > k) zl = fmaf(-a[k], zk, zl);
        }
        #pragma unroll
        for (int k = 31; k >= 0; --k) {
            float akk = __shfl(a[k], k);
            float wk = __shfl(zl, k) / akk;
            if (tid == k) zl = wk;
            else if (tid < k) zl = fmaf(-Af[k * 33 + tid], wk, zl);
        }
        wt[tid] = zl;
    }
    __syncthreads();

    const int sstep = step_s;
    const float* xrow = x + (size_t)(b * SS + sstep) * TXX;
    for (int i = tid; i < TXX; i += 256) xsr[i] = xrow[i];
    __syncthreads();
    float pk = 0.f;
    #pragma unroll
    for (int l = 0; l < FILT; ++l) pk = fmaf(xsr[tid + l], wt[l], pk);
    float d = y[(size_t)(b * SS + sstep) * TYY + tid] - pk;
    red[tid] = d * d;
    __syncthreads();
    for (int off = 128; off > 0; off >>= 1) {
        if (tid < off) red[tid] += red[tid + off];
        __syncthreads();
    }
    if (tid == 0) {
        float lossval = red[0] * (1.0f / TYY);
        float* loss_sum = (float*)(ctrs + 2);
        if (anyv) {
            atomicAdd(loss_sum, lossval);
            atomicAdd(&ctrs[1], 1);
        }
        __threadfence();
        int prev = atomicAdd(&ctrs[0], 1);
        if (prev == BB * NT - 1) {
            float s = atomicAdd(loss_sum, 0.0f);     // atomic read (device-coherent)
            int c = atomicAdd(&ctrs[1], 0);
            out0[0] = s / (float)(c > 0 ? c : 1);
        }
    }
}

extern "C" void kernel_launch(void* const* d_in, const int* in_sizes, int n_in,
                              void* d_out, int out_size, void* d_ws, size_t ws_size,
                              hipStream_t stream)
{
    const float* fps  = (const float*)d_in[0];
    const float* x    = (const float*)d_in[1];
    const float* y    = (const float*)d_in[2];
    const int* steps  = (const int*)d_in[3];
    const float* W1   = (const float*)d_in[4];
    const float* b1   = (const float*)d_in[5];
    const float* gamma= (const float*)d_in[6];
    const float* beta = (const float*)d_in[7];
    const float* W2   = (const float*)d_in[8];
    const float* b2   = (const float*)d_in[9];
    const float* Wq   = (const float*)d_in[10];
    const float* bq   = (const float*)d_in[11];
    const float* Wk   = (const float*)d_in[12];
    const float* bk   = (const float*)d_in[13];

    // Output f32 flat: [loss(1) | alpha(B*S*S) | e_orig(B*S*D)]
    float* out   = (float*)d_out;
    float* alpha = out + 1;
    float* e_out = out + 1 + (size_t)BB * SS * SS;

    // ws: [part(22.3MB) | gram(348KB) | ctrs(4 int) | q | kT]  (~27MB of 256MB)
    float* part = (float*)d_ws;
    float* gram = part + PARTTOT;
    int*   ctrs = (int*)(gram + GRAMTOT);
    float* q    = (float*)(ctrs + 4);
    float* kT   = q + (size_t)BB * SS * DMODEL;

    const int C = NCH, CS = SS / NCH;

    hipLaunchKernelGGL(k_mlp, dim3(BB * SS / 8), dim3(256), 0, stream,
                       fps, W1, b1, gamma, beta, W2, b2, Wq, bq, Wk, bk,
                       e_out, q, kT, ctrs);
    hipLaunchKernelGGL(k_attn, dim3(BB * (SS / 8)), dim3(256), 0, stream,
                       q, kT, alpha);
    hipLaunchKernelGGL(k_gpart, dim3(BB * C), dim3(256), 0, stream,
                       x, y, steps, alpha, part, C, CS);
    hipLaunchKernelGGL(k_reduce, dim3((BB * NT * GRAMN / 2) / 256), dim3(256), 0, stream,
                       part, gram);
    hipLaunchKernelGGL(k_solve2, dim3(BB * NT), dim3(256), 0, stream,
                       x, y, steps, alpha, gram, ctrs, out);
}

// Round 4
// 194.772 us; speedup vs baseline: 1.0940x; 1.0285x over previous
//
#include <hip/hip_runtime.h>
#include <math.h>

#define BB 16
#define SS 512
#define INDIM 64
#define DMODEL 64
#define HID 256
#define FILT 32
#define TYY 256
#define TXX 287
#define NT 5
#define RIDGEF 0.01f
#define THRESHF 0.005f
#define GRAMN 1088              // per-(b,t): 1056 pitch-33 gram + 32 cross
#define GRAMTOT (BB * NT * GRAMN)   // 87040 floats

// fast tanh: clamped exp2-path (v_exp_f32), |err| ~1e-6, no libcall
__device__ __forceinline__ float ftanh(float v)
{
    float vc = fminf(fmaxf(v, -15.f), 15.f);
    float e = __expf(2.f * vc);
    return (e - 1.f) / (e + 1.f);
}

// ---------------------------------------------------------------------------
// Kernel 1: fused MLP -> LN -> tanh -> W2 -> tanh (e_orig) -> +pos-enc -> q,kT.
// 8 rows/block, SINGLE pass (8-row W2/Wq/Wk phases, 6 barriers vs 11).
// Broadcast operands transposed in LDS: [i][r] layout -> 2x ds_read_b128
// broadcast per K-iter instead of 8x ds_read_b32.
// Side-job: blocks 0..339 zero gram; block 340 zeros counters.
// ---------------------------------------------------------------------------
__global__ __launch_bounds__(256) void k_mlp(
    const float* __restrict__ fps, const float* __restrict__ W1, const float* __restrict__ b1,
    const float* __restrict__ gamma, const float* __restrict__ beta,
    const float* __restrict__ W2, const float* __restrict__ b2,
    const float* __restrict__ Wq, const float* __restrict__ bq,
    const float* __restrict__ Wk, const float* __restrict__ bk,
    float* __restrict__ e_out, float* __restrict__ q_out, float* __restrict__ kT_out,
    float* __restrict__ gram, int* __restrict__ ctrs)
{
    const int row0 = blockIdx.x << 3;
    const int tid = threadIdx.x;
    const int wid = tid >> 6, lane = tid & 63;

    if (blockIdx.x < GRAMTOT / 256) {
        gram[(size_t)blockIdx.x * 256 + tid] = 0.f;
    } else if (blockIdx.x == GRAMTOT / 256 && tid < 4) {
        ctrs[tid] = 0;   // [0]=done_ctr [1]=valid_cnt [2]=loss_sum bits [3]=pad
    }

    __shared__ __align__(16) float frt[INDIM][8];    // [i][r]
    __shared__ __align__(16) float tht[HID][8];      // [i][r]
    __shared__ __align__(16) float eet[DMODEL][8];   // [i][r]
    __shared__ float partq[4][8][DMODEL];
    __shared__ float partk[4][8][DMODEL];
    __shared__ float wred[4][8][2];

    { int r = tid >> 6, i = tid & 63;
      frt[i][r]     = fps[(row0 + r) * INDIM + i];
      frt[i][r + 4] = fps[(row0 + r + 4) * INDIM + i]; }
    __syncthreads();

    float h[8];
    float b1v = b1[tid];
    #pragma unroll
    for (int r = 0; r < 8; ++r) h[r] = b1v;
    for (int i = 0; i < INDIM; ++i) {
        float w = W1[i * HID + tid];
        float4 f0 = *(const float4*)&frt[i][0];
        float4 f1 = *(const float4*)&frt[i][4];
        h[0] = fmaf(f0.x, w, h[0]); h[1] = fmaf(f0.y, w, h[1]);
        h[2] = fmaf(f0.z, w, h[2]); h[3] = fmaf(f0.w, w, h[3]);
        h[4] = fmaf(f1.x, w, h[4]); h[5] = fmaf(f1.y, w, h[5]);
        h[6] = fmaf(f1.z, w, h[6]); h[7] = fmaf(f1.w, w, h[7]);
    }

    float s1[8], s2[8];
    #pragma unroll
    for (int r = 0; r < 8; ++r) { s1[r] = h[r]; s2[r] = h[r] * h[r]; }
    #pragma unroll
    for (int off = 1; off < 64; off <<= 1) {
        #pragma unroll
        for (int r = 0; r < 8; ++r) {
            s1[r] += __shfl_xor(s1[r], off);
            s2[r] += __shfl_xor(s2[r], off);
        }
    }
    if (lane == 0) {
        #pragma unroll
        for (int r = 0; r < 8; ++r) { wred[wid][r][0] = s1[r]; wred[wid][r][1] = s2[r]; }
    }
    __syncthreads();
    float gm = gamma[tid], bt = beta[tid];
    float thv[8];
    #pragma unroll
    for (int r = 0; r < 8; ++r) {
        float t1 = wred[0][r][0] + wred[1][r][0] + wred[2][r][0] + wred[3][r][0];
        float t2 = wred[0][r][1] + wred[1][r][1] + wred[2][r][1] + wred[3][r][1];
        float mu = t1 * (1.0f / HID);
        float var = t2 * (1.0f / HID) - mu * mu;
        float hn = (h[r] - mu) * rsqrtf(var + 1e-5f) * gm + bt;
        thv[r] = ftanh(hn);
    }
    *(float4*)&tht[tid][0] = make_float4(thv[0], thv[1], thv[2], thv[3]);
    *(float4*)&tht[tid][4] = make_float4(thv[4], thv[5], thv[6], thv[7]);
    __syncthreads();

    { int p = tid >> 6, j = tid & 63;
      float acc[8] = {0.f, 0.f, 0.f, 0.f, 0.f, 0.f, 0.f, 0.f};
      for (int i = p * 64; i < p * 64 + 64; ++i) {
          float w = W2[i * DMODEL + j];
          float4 t0 = *(const float4*)&tht[i][0];
          float4 t1 = *(const float4*)&tht[i][4];
          acc[0] = fmaf(t0.x, w, acc[0]); acc[1] = fmaf(t0.y, w, acc[1]);
          acc[2] = fmaf(t0.z, w, acc[2]); acc[3] = fmaf(t0.w, w, acc[3]);
          acc[4] = fmaf(t1.x, w, acc[4]); acc[5] = fmaf(t1.y, w, acc[5]);
          acc[6] = fmaf(t1.z, w, acc[6]); acc[7] = fmaf(t1.w, w, acc[7]);
      }
      #pragma unroll
      for (int r = 0; r < 8; ++r) partq[p][r][j] = acc[r];
    }
    __syncthreads();

    { int r = tid >> 6, j = tid & 63;
      #pragma unroll
      for (int rr = r; rr < 8; rr += 4) {
          float e = partq[0][rr][j] + partq[1][rr][j] + partq[2][rr][j] + partq[3][rr][j] + b2[j];
          float eo = ftanh(e);
          int row = row0 + rr;
          int s = row & (SS - 1);
          e_out[(size_t)row * DMODEL + j] = eo;
          float div = __expf(-(float)(j & ~1) * 0.14391156831212787f);  // ln(10000)/64
          float ang = (float)s * div;
          float pe = (j & 1) ? __cosf(ang) : __sinf(ang);
          eet[j][rr] = eo + 0.05f * pe;
      }
    }
    __syncthreads();

    { int p = tid >> 6, j = tid & 63;
      float aq[8] = {0.f,0.f,0.f,0.f,0.f,0.f,0.f,0.f};
      float ak[8] = {0.f,0.f,0.f,0.f,0.f,0.f,0.f,0.f};
      for (int i = p * 16; i < p * 16 + 16; ++i) {
          float wqv = Wq[i * DMODEL + j];
          float wkv = Wk[i * DMODEL + j];
          float4 e0 = *(const float4*)&eet[i][0];
          float4 e1 = *(const float4*)&eet[i][4];
          aq[0] = fmaf(e0.x, wqv, aq[0]); aq[1] = fmaf(e0.y, wqv, aq[1]);
          aq[2] = fmaf(e0.z, wqv, aq[2]); aq[3] = fmaf(e0.w, wqv, aq[3]);
          aq[4] = fmaf(e1.x, wqv, aq[4]); aq[5] = fmaf(e1.y, wqv, aq[5]);
          aq[6] = fmaf(e1.z, wqv, aq[6]); aq[7] = fmaf(e1.w, wqv, aq[7]);
          ak[0] = fmaf(e0.x, wkv, ak[0]); ak[1] = fmaf(e0.y, wkv, ak[1]);
          ak[2] = fmaf(e0.z, wkv, ak[2]); ak[3] = fmaf(e0.w, wkv, ak[3]);
          ak[4] = fmaf(e1.x, wkv, ak[4]); ak[5] = fmaf(e1.y, wkv, ak[5]);
          ak[6] = fmaf(e1.z, wkv, ak[6]); ak[7] = fmaf(e1.w, wkv, ak[7]);
      }
      #pragma unroll
      for (int r = 0; r < 8; ++r) { partq[p][r][j] = aq[r]; partk[p][r][j] = ak[r]; }
    }
    __syncthreads();

    { int r = tid >> 6, j = tid & 63;
      #pragma unroll
      for (int rr = r; rr < 8; rr += 4) {
          float qv = partq[0][rr][j] + partq[1][rr][j] + partq[2][rr][j] + partq[3][rr][j] + bq[j];
          float kv = partk[0][rr][j] + partk[1][rr][j] + partk[2][rr][j] + partk[3][rr][j] + bk[j];
          int row = row0 + rr;
          int b = row >> 9, s = row & (SS - 1);
          q_out[(size_t)row * DMODEL + j] = qv;
          kT_out[(size_t)(b * DMODEL + j) * SS + s] = kv;
      }
    }
}

// ---------------------------------------------------------------------------
// Kernel 2: causal scores + softmax -> alpha f32 into d_out.
// 8 t-rows per block; q transposed in LDS (2x b128 broadcast per d);
// causal wave-skip: waves whose whole s-range is masked skip the dot loop
// (exact: they produced exp(-inf)=0 anyway).
// ---------------------------------------------------------------------------
__global__ __launch_bounds__(256) void k_attn(
    const float* __restrict__ q, const float* __restrict__ kT,
    float* __restrict__ alpha)
{
    const int blk = blockIdx.x;
    const int b = blk >> 6;              // 64 blocks per batch
    const int t0 = (blk & 63) << 3;
    const int t7 = t0 + 7;
    const int tid = threadIdx.x;
    const int wave = tid >> 6, lane = tid & 63;

    __shared__ __align__(16) float qtt[DMODEL][8];   // [d][r]
    __shared__ float redm[8][4];

    { size_t qb = (size_t)(b * SS + t0) * DMODEL;
      int r = tid >> 6, d = tid & 63;
      qtt[d][r]     = q[qb + tid];
      qtt[d][r + 4] = q[qb + tid + 256]; }
    __syncthreads();

    const float* kTb = kT + (size_t)b * DMODEL * SS;
    const int s0 = tid, s1 = tid + 256;
    float a0[8] = {0,0,0,0,0,0,0,0}, a1[8] = {0,0,0,0,0,0,0,0};
    const bool live0 = (wave << 6) <= t7;          // wave's min s0 unmasked?
    const bool live1 = ((wave << 6) + 256) <= t7;  // wave's min s1 unmasked?
    if (live1) {
        for (int d = 0; d < DMODEL; ++d) {
            float k0 = kTb[d * SS + s0];
            float k1 = kTb[d * SS + s1];
            float4 q0 = *(const float4*)&qtt[d][0];
            float4 q1 = *(const float4*)&qtt[d][4];
            a0[0] = fmaf(q0.x, k0, a0[0]); a1[0] = fmaf(q0.x, k1, a1[0]);
            a0[1] = fmaf(q0.y, k0, a0[1]); a1[1] = fmaf(q0.y, k1, a1[1]);
            a0[2] = fmaf(q0.z, k0, a0[2]); a1[2] = fmaf(q0.z, k1, a1[2]);
            a0[3] = fmaf(q0.w, k0, a0[3]); a1[3] = fmaf(q0.w, k1, a1[3]);
            a0[4] = fmaf(q1.x, k0, a0[4]); a1[4] = fmaf(q1.x, k1, a1[4]);
            a0[5] = fmaf(q1.y, k0, a0[5]); a1[5] = fmaf(q1.y, k1, a1[5]);
            a0[6] = fmaf(q1.z, k0, a0[6]); a1[6] = fmaf(q1.z, k1, a1[6]);
            a0[7] = fmaf(q1.w, k0, a0[7]); a1[7] = fmaf(q1.w, k1, a1[7]);
        }
    } else if (live0) {
        for (int d = 0; d < DMODEL; ++d) {
            float k0 = kTb[d * SS + s0];
            float4 q0 = *(const float4*)&qtt[d][0];
            float4 q1 = *(const float4*)&qtt[d][4];
            a0[0] = fmaf(q0.x, k0, a0[0]); a0[1] = fmaf(q0.y, k0, a0[1]);
            a0[2] = fmaf(q0.z, k0, a0[2]); a0[3] = fmaf(q0.w, k0, a0[3]);
            a0[4] = fmaf(q1.x, k0, a0[4]); a0[5] = fmaf(q1.y, k0, a0[5]);
            a0[6] = fmaf(q1.z, k0, a0[6]); a0[7] = fmaf(q1.w, k0, a0[7]);
        }
    }
    float lg0[8], lg1[8];
    #pragma unroll
    for (int r = 0; r < 8; ++r) {
        int tr = t0 + r;
        lg0[r] = (s0 <= tr) ? 0.25f * a0[r] : -INFINITY;
        lg1[r] = (s1 <= tr) ? 0.25f * a1[r] : -INFINITY;
    }
    float mr[8];
    #pragma unroll
    for (int r = 0; r < 8; ++r) {
        float m = fmaxf(lg0[r], lg1[r]);
        #pragma unroll
        for (int off = 32; off > 0; off >>= 1) m = fmaxf(m, __shfl_xor(m, off));
        if (lane == 0) redm[r][wave] = m;
    }
    __syncthreads();
    #pragma unroll
    for (int r = 0; r < 8; ++r)
        mr[r] = fmaxf(fmaxf(redm[r][0], redm[r][1]), fmaxf(redm[r][2], redm[r][3]));
    __syncthreads();
    float ex0[8], ex1[8], sr[8];
    #pragma unroll
    for (int r = 0; r < 8; ++r) {
        ex0[r] = __expf(lg0[r] - mr[r]);   // exp(-inf) = 0 for masked
        ex1[r] = __expf(lg1[r] - mr[r]);
        float sm = ex0[r] + ex1[r];
        #pragma unroll
        for (int off = 32; off > 0; off >>= 1) sm += __shfl_xor(sm, off);
        if (lane == 0) redm[r][wave] = sm;
    }
    __syncthreads();
    #pragma unroll
    for (int r = 0; r < 8; ++r)
        sr[r] = redm[r][0] + redm[r][1] + redm[r][2] + redm[r][3];
    #pragma unroll
    for (int r = 0; r < 8; ++r) {
        float inv = 1.0f / sr[r];
        size_t base = (size_t)(b * SS + t0 + r) * SS;
        alpha[base + s0] = ex0[r] * inv;
        alpha[base + s1] = ex1[r] * inv;
    }
}

// ---------------------------------------------------------------------------
// Kernel 3: per (b, s-chunk); float4 dot loops, prefix-scan diagonals,
// register acc; ballot-compacted selection; atomicAdd into gram.
// (round-0 verified version: atomics measured ~free vs part+reduce path)
// ---------------------------------------------------------------------------
__global__ __launch_bounds__(256) void k_gpart(
    const float* __restrict__ x, const float* __restrict__ y,
    const int* __restrict__ steps, const float* __restrict__ alpha,
    float* __restrict__ gram, int C, int CS)
{
    const int b = blockIdx.x / C;
    const int chunk = blockIdx.x % C;
    const int tid = threadIdx.x;
    const int lane = tid & 63, wid = tid >> 6;

    __shared__ __align__(16) float xs[288];
    __shared__ __align__(16) float ys[256];
    __shared__ float Gs[1056];        // 32x33 (pitch 33)
    __shared__ float crossL[32];
    __shared__ float wv[NT * 64];
    __shared__ float wtot[NT];
    __shared__ int sl[64];
    __shared__ int nselS;
    __shared__ int stS[NT];
    __shared__ float redA[4][33];
    __shared__ float redB[4][33];

    if (tid < NT) stS[tid] = steps[tid];
    if (tid < 32) Gs[tid * 33 + 32] = 0.f;
    __syncthreads();

    for (int idx = tid; idx < NT * CS; idx += 256) {
        int t = idx / CS, si = idx % CS;
        float a = alpha[(size_t)(b * SS + stS[t]) * SS + chunk * CS + si];
        wv[t * 64 + si] = (a > THRESHF) ? a : 0.f;
    }
    __syncthreads();
    if (tid < NT) {
        float s = 0.f;
        for (int si = 0; si < CS; ++si) s += wv[tid * 64 + si];
        wtot[tid] = s;
    }
    if (wid == 0) {
        float m = 0.f;
        if (lane < CS)
            m = wv[lane] + wv[64 + lane] + wv[128 + lane] + wv[192 + lane] + wv[256 + lane];
        unsigned long long mask = __ballot(m > 0.f);
        if (m > 0.f) {
            int pos = __popcll(mask & ((1ull << lane) - 1ull));
            sl[pos] = lane;
        }
        if (lane == 0) nselS = __popcll(mask);
    }
    __syncthreads();
    const int nsel = nselS;

    float acc[NT][5];
    #pragma unroll
    for (int t = 0; t < NT; ++t) {
        #pragma unroll
        for (int r = 0; r < 5; ++r) acc[t][r] = 0.f;
    }

    float rx0 = 0.f, rx1 = 0.f, ry = 0.f;
    if (nsel > 0) {
        int sg = chunk * CS + sl[0];
        const float* xr = x + (size_t)(b * SS + sg) * TXX;
        const float* yr = y + (size_t)(b * SS + sg) * TYY;
        rx0 = xr[tid];
        if (tid < 31) rx1 = xr[256 + tid];
        ry = yr[tid];
    }

    for (int i = 0; i < nsel; ++i) {
        xs[tid] = rx0;
        if (tid < 31) xs[256 + tid] = rx1;
        ys[tid] = ry;
        const int sl_cur = sl[i];
        __syncthreads();

        if (i + 1 < nsel) {
            int sg = chunk * CS + sl[i + 1];
            const float* xr = x + (size_t)(b * SS + sg) * TXX;
            const float* yr = y + (size_t)(b * SS + sg) * TYY;
            rx0 = xr[tid];
            if (tid < 31) rx1 = xr[256 + tid];
            ry = yr[tid];
        }

        { int l = tid & 31, p = tid >> 5;
          const float4* xk4 = (const float4*)(xs + (p << 5));
          const float4* yk4 = (const float4*)(ys + (p << 5));
          float c = 0.f, a = 0.f;
          #pragma unroll
          for (int j = 0; j < 8; ++j) {
              float4 xk = xk4[j];
              float4 yk = yk4[j];
              int kb = (p << 5) + (j << 2);
              float x0 = xs[kb + l],     x1 = xs[kb + 1 + l];
              float x2 = xs[kb + 2 + l], x3 = xs[kb + 3 + l];
              c = fmaf(x0, yk.x, c); a = fmaf(xk.x, x0, a);
              c = fmaf(x1, yk.y, c); a = fmaf(xk.y, x1, a);
              c = fmaf(x2, yk.z, c); a = fmaf(xk.z, x2, a);
              c = fmaf(x3, yk.w, c); a = fmaf(xk.w, x3, a);
          }
          c += __shfl_xor(c, 32);
          a += __shfl_xor(a, 32);
          if (lane < 32) { redA[wid][l] = c; redB[wid][l] = a; }
        }
        __syncthreads();

        if (tid < 32)
            crossL[tid] = redA[0][tid] + redA[1][tid] + redA[2][tid] + redA[3][tid];

        { int jj = lane & 31;
          #pragma unroll
          for (int pass = 0; pass < 4; ++pass) {
              int dd = 2 * (wid + 4 * pass) + (lane >> 5);
              float g0 = redB[0][dd] + redB[1][dd] + redB[2][dd] + redB[3][dd];
              float dlt = 0.f;
              if (jj > 0 && jj + dd < 32)
                  dlt = xs[jj + 255] * xs[jj + 255 + dd]
                      - xs[jj - 1] * xs[jj - 1 + dd];
              #pragma unroll
              for (int off = 1; off < 32; off <<= 1) {
                  float tsh = __shfl_up(dlt, off, 32);
                  if (jj >= off) dlt += tsh;
              }
              if (jj + dd < 32) {
                  float gval = g0 + dlt;
                  Gs[jj * 33 + jj + dd] = gval;
                  Gs[(jj + dd) * 33 + jj] = gval;
              }
          }
        }
        __syncthreads();

        { float g0 = Gs[tid], g1 = Gs[tid + 256], g2 = Gs[tid + 512], g3 = Gs[tid + 768];
          float g4 = (tid < 32) ? Gs[1024 + tid]
                   : ((tid < 64) ? crossL[tid - 32] : 0.f);
          #pragma unroll
          for (int t = 0; t < NT; ++t) {
              float w = wv[t * 64 + sl_cur];
              if (w > 0.f) {
                  acc[t][0] = fmaf(w, g0, acc[t][0]);
                  acc[t][1] = fmaf(w, g1, acc[t][1]);
                  acc[t][2] = fmaf(w, g2, acc[t][2]);
                  acc[t][3] = fmaf(w, g3, acc[t][3]);
                  acc[t][4] = fmaf(w, g4, acc[t][4]);
              }
          }
        }
    }

    #pragma unroll
    for (int t = 0; t < NT; ++t) {
        if (wtot[t] > 0.f) {
            float* gr = gram + (size_t)(b * NT + t) * GRAMN;
            #pragma unroll
            for (int r = 0; r < 4; ++r) atomicAdd(&gr[tid + 256 * r], acc[t][r]);
            if (tid < 64) atomicAdd(&gr[1024 + tid], acc[t][4]);
        }
    }
}

// ---------------------------------------------------------------------------
// Kernel 4: per (b,t): gram row + ridge, single-wave register Cholesky,
// shuffle solves, prediction loss; masked-mean via atomics + last-block.
// ---------------------------------------------------------------------------
__global__ __launch_bounds__(256) void k_solve2(
    const float* __restrict__ x, const float* __restrict__ y,
    const int* __restrict__ steps, const float* __restrict__ alpha,
    const float* __restrict__ gram,
    int* __restrict__ ctrs, float* __restrict__ out0)
{
    const int g = blockIdx.x;
    const int b = g / NT, t = g % NT;
    const int tid = threadIdx.x;

    __shared__ float Af[1056];   // pitch 33
    __shared__ float zs[FILT];
    __shared__ float wt[FILT];
    __shared__ float xsr[TXX + 1];
    __shared__ float red[256];
    __shared__ int step_s;
    __shared__ int anyv;

    if (tid == 0) { step_s = steps[t]; anyv = 0; }
    __syncthreads();

    const float* row = gram + (size_t)g * GRAMN;
    Af[tid] = row[tid];
    Af[tid + 256] = row[tid + 256];
    Af[tid + 512] = row[tid + 512];
    Af[tid + 768] = row[tid + 768];
    if (tid < 32) Af[1024 + tid] = row[1024 + tid];
    else if (tid < 64) zs[tid - 32] = row[1024 + tid];

    { const float* arow = alpha + (size_t)(b * SS + step_s) * SS;
      if (arow[tid] > THRESHF || arow[tid + 256] > THRESHF) anyv = 1; }
    __syncthreads();
    if (tid < 32) Af[tid * 33 + tid] += RIDGEF;
    __syncthreads();

    if (tid < 32) {
        float a[32];
        #pragma unroll
        for (int j = 0; j < 32; ++j) a[j] = Af[tid * 33 + j];
        #pragma unroll
        for (int k = 0; k < 32; ++k) {
            float akk = __shfl(a[k], k);
            float dk = sqrtf(akk);
            float ck = a[k] / dk;
            if (tid >= k) a[k] = ck;
            #pragma unroll
            for (int m = k + 1; m < 32; ++m) {
                float cm = __shfl(ck, m);
                if (tid >= m) a[m] = fmaf(-ck, cm, a[m]);
            }
        }
        #pragma unroll
        for (int j = 0; j < 32; ++j)
            if (j <= tid) Af[tid * 33 + j] = a[j];

        float zl = zs[tid];
        #pragma unroll
        for (int k = 0; k < 32; ++k) {
            float akk = __shfl(a[k], k);
            float zk = __shfl(zl, k) / akk;
            if (tid == k) zl = zk;
            else if (tid > k) zl = fmaf(-a[k], zk, zl);
        }
        #pragma unroll
        for (int k = 31; k >= 0; --k) {
            float akk = __shfl(a[k], k);
            float wk = __shfl(zl, k) / akk;
            if (tid == k) zl = wk;
            else if (tid < k) zl = fmaf(-Af[k * 33 + tid], wk, zl);
        }
        wt[tid] = zl;
    }
    __syncthreads();

    const int sstep = step_s;
    const float* xrow = x + (size_t)(b * SS + sstep) * TXX;
    for (int i = tid; i < TXX; i += 256) xsr[i] = xrow[i];
    __syncthreads();
    float pk = 0.f;
    #pragma unroll
    for (int l = 0; l < FILT; ++l) pk = fmaf(xsr[tid + l], wt[l], pk);
    float d = y[(size_t)(b * SS + sstep) * TYY + tid] - pk;
    red[tid] = d * d;
    __syncthreads();
    for (int off = 128; off > 0; off >>= 1) {
        if (tid < off) red[tid] += red[tid + off];
        __syncthreads();
    }
    if (tid == 0) {
        float lossval = red[0] * (1.0f / TYY);
        float* loss_sum = (float*)(ctrs + 2);
        if (anyv) {
            atomicAdd(loss_sum, lossval);
            atomicAdd(&ctrs[1], 1);
        }
        __threadfence();
        int prev = atomicAdd(&ctrs[0], 1);
        if (prev == BB * NT - 1) {
            float s = atomicAdd(loss_sum, 0.0f);     // atomic read (device-coherent)
            int c = atomicAdd(&ctrs[1], 0);
            out0[0] = s / (float)(c > 0 ? c : 1);
        }
    }
}

extern "C" void kernel_launch(void* const* d_in, const int* in_sizes, int n_in,
                              void* d_out, int out_size, void* d_ws, size_t ws_size,
                              hipStream_t stream)
{
    const float* fps  = (const float*)d_in[0];
    const float* x    = (const float*)d_in[1];
    const float* y    = (const float*)d_in[2];
    const int* steps  = (const int*)d_in[3];
    const float* W1   = (const float*)d_in[4];
    const float* b1   = (const float*)d_in[5];
    const float* gamma= (const float*)d_in[6];
    const float* beta = (const float*)d_in[7];
    const float* W2   = (const float*)d_in[8];
    const float* b2   = (const float*)d_in[9];
    const float* Wq   = (const float*)d_in[10];
    const float* bq   = (const float*)d_in[11];
    const float* Wk   = (const float*)d_in[12];
    const float* bk   = (const float*)d_in[13];

    // Output f32 flat: [loss(1) | alpha(B*S*S) | e_orig(B*S*D)]
    float* out   = (float*)d_out;
    float* alpha = out + 1;
    float* e_out = out + 1 + (size_t)BB * SS * SS;

    // ws: [gram(80*1088) | ctrs(4 int) | q | kT]
    float* gram = (float*)d_ws;
    int*   ctrs = (int*)(gram + GRAMTOT);
    float* q    = (float*)(ctrs + 4);
    float* kT   = q + (size_t)BB * SS * DMODEL;

    const int C = 64, CS = SS / 64;

    hipLaunchKernelGGL(k_mlp, dim3(BB * SS / 8), dim3(256), 0, stream,
                       fps, W1, b1, gamma, beta, W2, b2, Wq, bq, Wk, bk,
                       e_out, q, kT, gram, ctrs);
    hipLaunchKernelGGL(k_attn, dim3(BB * (SS / 8)), dim3(256), 0, stream,
                       q, kT, alpha);
    hipLaunchKernelGGL(k_gpart, dim3(BB * C), dim3(256), 0, stream,
                       x, y, steps, alpha, gram, C, CS);
    hipLaunchKernelGGL(k_solve2, dim3(BB * NT), dim3(256), 0, stream,
                       x, y, steps, alpha, gram, ctrs, out);
}

// Round 6
// 174.993 us; speedup vs baseline: 1.2176x; 1.1130x over previous
//
#include <hip/hip_runtime.h>
#include <math.h>

#define BB 16
#define SS 512
#define INDIM 64
#define DMODEL 64
#define HID 256
#define FILT 32
#define TYY 256
#define TXX 287
#define NT 5
#define RIDGEF 0.01f
#define THRESHF 0.005f
#define GRAMN 1088              // per-(b,t): 1056 pitch-33 gram + 32 cross
#define GRAMTOT (BB * NT * GRAMN)   // 87040 floats

// fast tanh: clamped exp2-path (v_exp_f32), |err| ~1e-6, no libcall
__device__ __forceinline__ float ftanh(float v)
{
    float vc = fminf(fmaxf(v, -15.f), 15.f);
    float e = __expf(2.f * vc);
    return (e - 1.f) / (e + 1.f);
}

// ---------------------------------------------------------------------------
// Kernel 1: fused MLP -> LN -> tanh -> W2 -> tanh (e_orig) -> +pos-enc -> q,kT.
// 4 rows/block, 2048 blocks (8 blocks/CU = 32 waves/CU, occupancy-doubling
// vs the 8-row/1024-block version: latency-hiding was the R5 theory).
// Side-job: blocks 0..339 zero gram; block 340 zeros counters.
// ---------------------------------------------------------------------------
__global__ __launch_bounds__(256) void k_mlp(
    const float* __restrict__ fps, const float* __restrict__ W1, const float* __restrict__ b1,
    const float* __restrict__ gamma, const float* __restrict__ beta,
    const float* __restrict__ W2, const float* __restrict__ b2,
    const float* __restrict__ Wq, const float* __restrict__ bq,
    const float* __restrict__ Wk, const float* __restrict__ bk,
    float* __restrict__ e_out, float* __restrict__ q_out, float* __restrict__ kT_out,
    float* __restrict__ gram, int* __restrict__ ctrs)
{
    const int row0 = blockIdx.x << 2;
    const int tid = threadIdx.x;
    const int wid = tid >> 6, lane = tid & 63;

    if (blockIdx.x < GRAMTOT / 256) {
        gram[(size_t)blockIdx.x * 256 + tid] = 0.f;
    } else if (blockIdx.x == GRAMTOT / 256 && tid < 4) {
        ctrs[tid] = 0;   // [0]=done_ctr [1]=valid_cnt [2]=loss_sum bits [3]=pad
    }

    __shared__ __align__(16) float frt[INDIM][4];    // [i][r]
    __shared__ __align__(16) float tht[HID][4];      // [i][r]
    __shared__ __align__(16) float eet[DMODEL][4];   // [i][r]
    __shared__ float partq[4][4][DMODEL];
    __shared__ float partk[4][4][DMODEL];
    __shared__ float wred[4][4][2];

    { int r = tid >> 6, i = tid & 63;
      frt[i][r] = fps[(row0 + r) * INDIM + i]; }
    __syncthreads();

    float h[4];
    float b1v = b1[tid];
    #pragma unroll
    for (int r = 0; r < 4; ++r) h[r] = b1v;
    for (int i = 0; i < INDIM; ++i) {
        float w = W1[i * HID + tid];
        float4 f0 = *(const float4*)&frt[i][0];
        h[0] = fmaf(f0.x, w, h[0]); h[1] = fmaf(f0.y, w, h[1]);
        h[2] = fmaf(f0.z, w, h[2]); h[3] = fmaf(f0.w, w, h[3]);
    }

    float s1[4], s2[4];
    #pragma unroll
    for (int r = 0; r < 4; ++r) { s1[r] = h[r]; s2[r] = h[r] * h[r]; }
    #pragma unroll
    for (int off = 1; off < 64; off <<= 1) {
        #pragma unroll
        for (int r = 0; r < 4; ++r) {
            s1[r] += __shfl_xor(s1[r], off);
            s2[r] += __shfl_xor(s2[r], off);
        }
    }
    if (lane == 0) {
        #pragma unroll
        for (int r = 0; r < 4; ++r) { wred[wid][r][0] = s1[r]; wred[wid][r][1] = s2[r]; }
    }
    __syncthreads();
    float gm = gamma[tid], bt = beta[tid];
    float thv[4];
    #pragma unroll
    for (int r = 0; r < 4; ++r) {
        float t1 = wred[0][r][0] + wred[1][r][0] + wred[2][r][0] + wred[3][r][0];
        float t2 = wred[0][r][1] + wred[1][r][1] + wred[2][r][1] + wred[3][r][1];
        float mu = t1 * (1.0f / HID);
        float var = t2 * (1.0f / HID) - mu * mu;
        float hn = (h[r] - mu) * rsqrtf(var + 1e-5f) * gm + bt;
        thv[r] = ftanh(hn);
    }
    *(float4*)&tht[tid][0] = make_float4(thv[0], thv[1], thv[2], thv[3]);
    __syncthreads();

    { int p = tid >> 6, j = tid & 63;
      float acc[4] = {0.f, 0.f, 0.f, 0.f};
      for (int i = p * 64; i < p * 64 + 64; ++i) {
          float w = W2[i * DMODEL + j];
          float4 t0 = *(const float4*)&tht[i][0];
          acc[0] = fmaf(t0.x, w, acc[0]); acc[1] = fmaf(t0.y, w, acc[1]);
          acc[2] = fmaf(t0.z, w, acc[2]); acc[3] = fmaf(t0.w, w, acc[3]);
      }
      #pragma unroll
      for (int r = 0; r < 4; ++r) partq[p][r][j] = acc[r];
    }
    __syncthreads();

    { int r = tid >> 6, j = tid & 63;
      float e = partq[0][r][j] + partq[1][r][j] + partq[2][r][j] + partq[3][r][j] + b2[j];
      float eo = ftanh(e);
      int row = row0 + r;
      int s = row & (SS - 1);
      e_out[(size_t)row * DMODEL + j] = eo;
      float div = __expf(-(float)(j & ~1) * 0.14391156831212787f);  // ln(10000)/64
      float ang = (float)s * div;
      float pe = (j & 1) ? __cosf(ang) : __sinf(ang);
      eet[j][r] = eo + 0.05f * pe;
    }
    __syncthreads();

    { int p = tid >> 6, j = tid & 63;
      float aq[4] = {0.f,0.f,0.f,0.f}, ak[4] = {0.f,0.f,0.f,0.f};
      for (int i = p * 16; i < p * 16 + 16; ++i) {
          float wqv = Wq[i * DMODEL + j];
          float wkv = Wk[i * DMODEL + j];
          float4 e0 = *(const float4*)&eet[i][0];
          aq[0] = fmaf(e0.x, wqv, aq[0]); aq[1] = fmaf(e0.y, wqv, aq[1]);
          aq[2] = fmaf(e0.z, wqv, aq[2]); aq[3] = fmaf(e0.w, wqv, aq[3]);
          ak[0] = fmaf(e0.x, wkv, ak[0]); ak[1] = fmaf(e0.y, wkv, ak[1]);
          ak[2] = fmaf(e0.z, wkv, ak[2]); ak[3] = fmaf(e0.w, wkv, ak[3]);
      }
      #pragma unroll
      for (int r = 0; r < 4; ++r) { partq[p][r][j] = aq[r]; partk[p][r][j] = ak[r]; }
    }
    __syncthreads();

    { int r = tid >> 6, j = tid & 63;
      float qv = partq[0][r][j] + partq[1][r][j] + partq[2][r][j] + partq[3][r][j] + bq[j];
      float kv = partk[0][r][j] + partk[1][r][j] + partk[2][r][j] + partk[3][r][j] + bk[j];
      int row = row0 + r;
      int b = row >> 9, s = row & (SS - 1);
      q_out[(size_t)row * DMODEL + j] = qv;
      kT_out[(size_t)(b * DMODEL + j) * SS + s] = kv;
    }
}

// ---------------------------------------------------------------------------
// Kernel 2: causal scores + softmax -> alpha f32 into d_out.
// 4 t-rows per block, 2048 blocks (8 blocks/CU); fully-masked waves skip
// the dot loop (exact: they produced exp(-inf)=0 anyway).
// ---------------------------------------------------------------------------
__global__ __launch_bounds__(256) void k_attn(
    const float* __restrict__ q, const float* __restrict__ kT,
    float* __restrict__ alpha)
{
    const int blk = blockIdx.x;
    const int b = blk >> 7;              // 128 blocks per batch
    const int t0 = (blk & 127) << 2;
    const int t3 = t0 + 3;
    const int tid = threadIdx.x;
    const int wid = tid >> 6, lane = tid & 63;

    __shared__ __align__(16) float qtt[DMODEL][4];   // [d][r]
    __shared__ float redm[4][4];

    { size_t qb = (size_t)(b * SS + t0) * DMODEL;
      int r = tid >> 6, d = tid & 63;
      qtt[d][r] = q[qb + tid]; }
    __syncthreads();

    const float* kTb = kT + (size_t)b * DMODEL * SS;
    const int s0 = tid, s1 = tid + 256;
    float a0[4] = {0,0,0,0}, a1[4] = {0,0,0,0};
    const bool live0 = (wid << 6) <= t3;          // wave's min s0 unmasked?
    const bool live1 = ((wid << 6) + 256) <= t3;  // wave's min s1 unmasked?
    if (live1) {
        for (int d = 0; d < DMODEL; ++d) {
            float k0 = kTb[d * SS + s0];
            float k1 = kTb[d * SS + s1];
            float4 q0 = *(const float4*)&qtt[d][0];
            a0[0] = fmaf(q0.x, k0, a0[0]); a1[0] = fmaf(q0.x, k1, a1[0]);
            a0[1] = fmaf(q0.y, k0, a0[1]); a1[1] = fmaf(q0.y, k1, a1[1]);
            a0[2] = fmaf(q0.z, k0, a0[2]); a1[2] = fmaf(q0.z, k1, a1[2]);
            a0[3] = fmaf(q0.w, k0, a0[3]); a1[3] = fmaf(q0.w, k1, a1[3]);
        }
    } else if (live0) {
        for (int d = 0; d < DMODEL; ++d) {
            float k0 = kTb[d * SS + s0];
            float4 q0 = *(const float4*)&qtt[d][0];
            a0[0] = fmaf(q0.x, k0, a0[0]); a0[1] = fmaf(q0.y, k0, a0[1]);
            a0[2] = fmaf(q0.z, k0, a0[2]); a0[3] = fmaf(q0.w, k0, a0[3]);
        }
    }
    float lg0[4], lg1[4];
    #pragma unroll
    for (int r = 0; r < 4; ++r) {
        int tr = t0 + r;
        lg0[r] = (s0 <= tr) ? 0.25f * a0[r] : -INFINITY;
        lg1[r] = (s1 <= tr) ? 0.25f * a1[r] : -INFINITY;
    }
    float mr[4];
    #pragma unroll
    for (int r = 0; r < 4; ++r) {
        float m = fmaxf(lg0[r], lg1[r]);
        #pragma unroll
        for (int off = 32; off > 0; off >>= 1) m = fmaxf(m, __shfl_xor(m, off));
        if (lane == 0) redm[r][wid] = m;
    }
    __syncthreads();
    #pragma unroll
    for (int r = 0; r < 4; ++r)
        mr[r] = fmaxf(fmaxf(redm[r][0], redm[r][1]), fmaxf(redm[r][2], redm[r][3]));
    __syncthreads();
    float ex0[4], ex1[4], sr[4];
    #pragma unroll
    for (int r = 0; r < 4; ++r) {
        ex0[r] = __expf(lg0[r] - mr[r]);   // exp(-inf) = 0 for masked
        ex1[r] = __expf(lg1[r] - mr[r]);
        float sm = ex0[r] + ex1[r];
        #pragma unroll
        for (int off = 32; off > 0; off >>= 1) sm += __shfl_xor(sm, off);
        if (lane == 0) redm[r][wid] = sm;
    }
    __syncthreads();
    #pragma unroll
    for (int r = 0; r < 4; ++r)
        sr[r] = redm[r][0] + redm[r][1] + redm[r][2] + redm[r][3];
    #pragma unroll
    for (int r = 0; r < 4; ++r) {
        float inv = 1.0f / sr[r];
        size_t base = (size_t)(b * SS + t0 + r) * SS;
        alpha[base + s0] = ex0[r] * inv;
        alpha[base + s1] = ex1[r] * inv;
    }
}

// ---------------------------------------------------------------------------
// Kernel 3: per (b, s-chunk); float4 dot loops, prefix-scan diagonals,
// register acc; ballot-compacted selection; atomicAdd into gram.
// CS=4 (128 chunks/batch, 2048 blocks): halves per-block serial nsel loop,
// doubles TLP.
// ---------------------------------------------------------------------------
__global__ __launch_bounds__(256) void k_gpart(
    const float* __restrict__ x, const float* __restrict__ y,
    const int* __restrict__ steps, const float* __restrict__ alpha,
    float* __restrict__ gram, int C, int CS)
{
    const int b = blockIdx.x / C;
    const int chunk = blockIdx.x % C;
    const int tid = threadIdx.x;
    const int lane = tid & 63, wid = tid >> 6;

    __shared__ __align__(16) float xs[288];
    __shared__ __align__(16) float ys[256];
    __shared__ float Gs[1056];        // 32x33 (pitch 33)
    __shared__ float crossL[32];
    __shared__ float wv[NT * 64];
    __shared__ float wtot[NT];
    __shared__ int sl[64];
    __shared__ int nselS;
    __shared__ int stS[NT];
    __shared__ float redA[4][33];
    __shared__ float redB[4][33];

    if (tid < NT) stS[tid] = steps[tid];
    if (tid < 32) Gs[tid * 33 + 32] = 0.f;
    __syncthreads();

    for (int idx = tid; idx < NT * CS; idx += 256) {
        int t = idx / CS, si = idx % CS;
        float a = alpha[(size_t)(b * SS + stS[t]) * SS + chunk * CS + si];
        wv[t * 64 + si] = (a > THRESHF) ? a : 0.f;
    }
    __syncthreads();
    if (tid < NT) {
        float s = 0.f;
        for (int si = 0; si < CS; ++si) s += wv[tid * 64 + si];
        wtot[tid] = s;
    }
    if (wid == 0) {
        float m = 0.f;
        if (lane < CS)
            m = wv[lane] + wv[64 + lane] + wv[128 + lane] + wv[192 + lane] + wv[256 + lane];
        unsigned long long mask = __ballot(m > 0.f);
        if (m > 0.f) {
            int pos = __popcll(mask & ((1ull << lane) - 1ull));
            sl[pos] = lane;
        }
        if (lane == 0) nselS = __popcll(mask);
    }
    __syncthreads();
    const int nsel = nselS;

    float acc[NT][5];
    #pragma unroll
    for (int t = 0; t < NT; ++t) {
        #pragma unroll
        for (int r = 0; r < 5; ++r) acc[t][r] = 0.f;
    }

    float rx0 = 0.f, rx1 = 0.f, ry = 0.f;
    if (nsel > 0) {
        int sg = chunk * CS + sl[0];
        const float* xr = x + (size_t)(b * SS + sg) * TXX;
        const float* yr = y + (size_t)(b * SS + sg) * TYY;
        rx0 = xr[tid];
        if (tid < 31) rx1 = xr[256 + tid];
        ry = yr[tid];
    }

    for (int i = 0; i < nsel; ++i) {
        xs[tid] = rx0;
        if (tid < 31) xs[256 + tid] = rx1;
        ys[tid] = ry;
        const int sl_cur = sl[i];
        __syncthreads();

        if (i + 1 < nsel) {
            int sg = chunk * CS + sl[i + 1];
            const float* xr = x + (size_t)(b * SS + sg) * TXX;
            const float* yr = y + (size_t)(b * SS + sg) * TYY;
            rx0 = xr[tid];
            if (tid < 31) rx1 = xr[256 + tid];
            ry = yr[tid];
        }

        { int l = tid & 31, p = tid >> 5;
          const float4* xk4 = (const float4*)(xs + (p << 5));
          const float4* yk4 = (const float4*)(ys + (p << 5));
          float c = 0.f, a = 0.f;
          #pragma unroll
          for (int j = 0; j < 8; ++j) {
              float4 xk = xk4[j];
              float4 yk = yk4[j];
              int kb = (p << 5) + (j << 2);
              float x0 = xs[kb + l],     x1 = xs[kb + 1 + l];
              float x2 = xs[kb + 2 + l], x3 = xs[kb + 3 + l];
              c = fmaf(x0, yk.x, c); a = fmaf(xk.x, x0, a);
              c = fmaf(x1, yk.y, c); a = fmaf(xk.y, x1, a);
              c = fmaf(x2, yk.z, c); a = fmaf(xk.z, x2, a);
              c = fmaf(x3, yk.w, c); a = fmaf(xk.w, x3, a);
          }
          c += __shfl_xor(c, 32);
          a += __shfl_xor(a, 32);
          if (lane < 32) { redA[wid][l] = c; redB[wid][l] = a; }
        }
        __syncthreads();

        if (tid < 32)
            crossL[tid] = redA[0][tid] + redA[1][tid] + redA[2][tid] + redA[3][tid];

        { int jj = lane & 31;
          #pragma unroll
          for (int pass = 0; pass < 4; ++pass) {
              int dd = 2 * (wid + 4 * pass) + (lane >> 5);
              float g0 = redB[0][dd] + redB[1][dd] + redB[2][dd] + redB[3][dd];
              float dlt = 0.f;
              if (jj > 0 && jj + dd < 32)
                  dlt = xs[jj + 255] * xs[jj + 255 + dd]
                      - xs[jj - 1] * xs[jj - 1 + dd];
              #pragma unroll
              for (int off = 1; off < 32; off <<= 1) {
                  float tsh = __shfl_up(dlt, off, 32);
                  if (jj >= off) dlt += tsh;
              }
              if (jj + dd < 32) {
                  float gval = g0 + dlt;
                  Gs[jj * 33 + jj + dd] = gval;
                  Gs[(jj + dd) * 33 + jj] = gval;
              }
          }
        }
        __syncthreads();

        { float g0 = Gs[tid], g1 = Gs[tid + 256], g2 = Gs[tid + 512], g3 = Gs[tid + 768];
          float g4 = (tid < 32) ? Gs[1024 + tid]
                   : ((tid < 64) ? crossL[tid - 32] : 0.f);
          #pragma unroll
          for (int t = 0; t < NT; ++t) {
              float w = wv[t * 64 + sl_cur];
              if (w > 0.f) {
                  acc[t][0] = fmaf(w, g0, acc[t][0]);
                  acc[t][1] = fmaf(w, g1, acc[t][1]);
                  acc[t][2] = fmaf(w, g2, acc[t][2]);
                  acc[t][3] = fmaf(w, g3, acc[t][3]);
                  acc[t][4] = fmaf(w, g4, acc[t][4]);
              }
          }
        }
    }

    #pragma unroll
    for (int t = 0; t < NT; ++t) {
        if (wtot[t] > 0.f) {
            float* gr = gram + (size_t)(b * NT + t) * GRAMN;
            #pragma unroll
            for (int r = 0; r < 4; ++r) atomicAdd(&gr[tid + 256 * r], acc[t][r]);
            if (tid < 64) atomicAdd(&gr[1024 + tid], acc[t][4]);
        }
    }
}

// ---------------------------------------------------------------------------
// Kernel 4: per (b,t): gram row + ridge, single-wave register Cholesky,
// shuffle solves, prediction loss; masked-mean via atomics + last-block.
// ---------------------------------------------------------------------------
__global__ __launch_bounds__(256) void k_solve2(
    const float* __restrict__ x, const float* __restrict__ y,
    const int* __restrict__ steps, const float* __restrict__ alpha,
    const float* __restrict__ gram,
    int* __restrict__ ctrs, float* __restrict__ out0)
{
    const int g = blockIdx.x;
    const int b = g / NT, t = g % NT;
    const int tid = threadIdx.x;

    __shared__ float Af[1056];   // pitch 33
    __shared__ float zs[FILT];
    __shared__ float wt[FILT];
    __shared__ float xsr[TXX + 1];
    __shared__ float red[256];
    __shared__ int step_s;
    __shared__ int anyv;

    if (tid == 0) { step_s = steps[t]; anyv = 0; }
    __syncthreads();

    const float* row = gram + (size_t)g * GRAMN;
    Af[tid] = row[tid];
    Af[tid + 256] = row[tid + 256];
    Af[tid + 512] = row[tid + 512];
    Af[tid + 768] = row[tid + 768];
    if (tid < 32) Af[1024 + tid] = row[1024 + tid];
    else if (tid < 64) zs[tid - 32] = row[1024 + tid];

    { const float* arow = alpha + (size_t)(b * SS + step_s) * SS;
      if (arow[tid] > THRESHF || arow[tid + 256] > THRESHF) anyv = 1; }
    __syncthreads();
    if (tid < 32) Af[tid * 33 + tid] += RIDGEF;
    __syncthreads();

    if (tid < 32) {
        float a[32];
        #pragma unroll
        for (int j = 0; j < 32; ++j) a[j] = Af[tid * 33 + j];
        #pragma unroll
        for (int k = 0; k < 32; ++k) {
            float akk = __shfl(a[k], k);
            float dk = sqrtf(akk);
            float ck = a[k] / dk;
            if (tid >= k) a[k] = ck;
            #pragma unroll
            for (int m = k + 1; m < 32; ++m) {
                float cm = __shfl(ck, m);
                if (tid >= m) a[m] = fmaf(-ck, cm, a[m]);
            }
        }
        #pragma unroll
        for (int j = 0; j < 32; ++j)
            if (j <= tid) Af[tid * 33 + j] = a[j];

        float zl = zs[tid];
        #pragma unroll
        for (int k = 0; k < 32; ++k) {
            float akk = __shfl(a[k], k);
            float zk = __shfl(zl, k) / akk;
            if (tid == k) zl = zk;
            else if (tid > k) zl = fmaf(-a[k], zk, zl);
        }
        #pragma unroll
        for (int k = 31; k >= 0; --k) {
            float akk = __shfl(a[k], k);
            float wk = __shfl(zl, k) / akk;
            if (tid == k) zl = wk;
            else if (tid < k) zl = fmaf(-Af[k * 33 + tid], wk, zl);
        }
        wt[tid] = zl;
    }
    __syncthreads();

    const int sstep = step_s;
    const float* xrow = x + (size_t)(b * SS + sstep) * TXX;
    for (int i = tid; i < TXX; i += 256) xsr[i] = xrow[i];
    __syncthreads();
    float pk = 0.f;
    #pragma unroll
    for (int l = 0; l < FILT; ++l) pk = fmaf(xsr[tid + l], wt[l], pk);
    float d = y[(size_t)(b * SS + sstep) * TYY + tid] - pk;
    red[tid] = d * d;
    __syncthreads();
    for (int off = 128; off > 0; off >>= 1) {
        if (tid < off) red[tid] += red[tid + off];
        __syncthreads();
    }
    if (tid == 0) {
        float lossval = red[0] * (1.0f / TYY);
        float* loss_sum = (float*)(ctrs + 2);
        if (anyv) {
            atomicAdd(loss_sum, lossval);
            atomicAdd(&ctrs[1], 1);
        }
        __threadfence();
        int prev = atomicAdd(&ctrs[0], 1);
        if (prev == BB * NT - 1) {
            float s = atomicAdd(loss_sum, 0.0f);     // atomic read (device-coherent)
            int c = atomicAdd(&ctrs[1], 0);
            out0[0] = s / (float)(c > 0 ? c : 1);
        }
    }
}

extern "C" void kernel_launch(void* const* d_in, const int* in_sizes, int n_in,
                              void* d_out, int out_size, void* d_ws, size_t ws_size,
                              hipStream_t stream)
{
    const float* fps  = (const float*)d_in[0];
    const float* x    = (const float*)d_in[1];
    const float* y    = (const float*)d_in[2];
    const int* steps  = (const int*)d_in[3];
    const float* W1   = (const float*)d_in[4];
    const float* b1   = (const float*)d_in[5];
    const float* gamma= (const float*)d_in[6];
    const float* beta = (const float*)d_in[7];
    const float* W2   = (const float*)d_in[8];
    const float* b2   = (const float*)d_in[9];
    const float* Wq   = (const float*)d_in[10];
    const float* bq   = (const float*)d_in[11];
    const float* Wk   = (const float*)d_in[12];
    const float* bk   = (const float*)d_in[13];

    // Output f32 flat: [loss(1) | alpha(B*S*S) | e_orig(B*S*D)]
    float* out   = (float*)d_out;
    float* alpha = out + 1;
    float* e_out = out + 1 + (size_t)BB * SS * SS;

    // ws: [gram(80*1088) | ctrs(4 int) | q | kT]
    float* gram = (float*)d_ws;
    int*   ctrs = (int*)(gram + GRAMTOT);
    float* q    = (float*)(ctrs + 4);
    float* kT   = q + (size_t)BB * SS * DMODEL;

    const int C = 128, CS = SS / 128;

    hipLaunchKernelGGL(k_mlp, dim3(BB * SS / 4), dim3(256), 0, stream,
                       fps, W1, b1, gamma, beta, W2, b2, Wq, bq, Wk, bk,
                       e_out, q, kT, gram, ctrs);
    hipLaunchKernelGGL(k_attn, dim3(BB * (SS / 4)), dim3(256), 0, stream,
                       q, kT, alpha);
    hipLaunchKernelGGL(k_gpart, dim3(BB * C), dim3(256), 0, stream,
                       x, y, steps, alpha, gram, C, CS);
    hipLaunchKernelGGL(k_solve2, dim3(BB * NT), dim3(256), 0, stream,
                       x, y, steps, alpha, gram, ctrs, out);
}